// Round 1
// baseline (1538.205 us; speedup 1.0000x reference)
//
#include <hip/hip_runtime.h>

#define T_  512
#define B_  256
#define F_  128
#define U_  128
#define G4_ 512

using f32x4 = __attribute__((ext_vector_type(4))) float;
using s16x8 = __attribute__((ext_vector_type(8))) short;
using s16x4 = __attribute__((ext_vector_type(4))) short;
using u32x4 = __attribute__((ext_vector_type(4))) unsigned int;

__device__ __forceinline__ unsigned fbits(float f) { return __builtin_bit_cast(unsigned, f); }

// fp32 -> bf16 round-to-nearest-even
__device__ __forceinline__ unsigned short f2bf(float f) {
  unsigned u = fbits(f);
  u += 0x7FFFu + ((u >> 16) & 1u);
  return (unsigned short)(u >> 16);
}
__device__ __forceinline__ float bf2f(unsigned short b) {
  return __builtin_bit_cast(float, (unsigned)b << 16);
}
// pack 8 fp32 -> 8 bf16 by truncation (v_perm grabs high halves); used for x only
__device__ __forceinline__ s16x8 pack8(f32x4 a, f32x4 b) {
  u32x4 w;
  w[0] = __builtin_amdgcn_perm(fbits(a[1]), fbits(a[0]), 0x07060302u);
  w[1] = __builtin_amdgcn_perm(fbits(a[3]), fbits(a[2]), 0x07060302u);
  w[2] = __builtin_amdgcn_perm(fbits(b[1]), fbits(b[0]), 0x07060302u);
  w[3] = __builtin_amdgcn_perm(fbits(b[3]), fbits(b[2]), 0x07060302u);
  return __builtin_bit_cast(s16x8, w);
}
// robust tanh: 2/(1+exp(-2x)) - 1  (saturates correctly for |x| large, no NaN)
__device__ __forceinline__ float tanh_fast(float x) {
  return __fdividef(2.0f, 1.0f + __expf(-2.0f * x)) - 1.0f;
}

__global__ __launch_bounds__(512, 2)
void lstm_seq_kernel(const float* __restrict__ X, const float* __restrict__ ST,
                     const float* __restrict__ DN, const float* __restrict__ WX,
                     const float* __restrict__ WH, float* __restrict__ OUT)
{
  // h exchange: [row 16][u 128] bf16, XOR-swizzled 8-elem slots (T2: breaks 16-way conflict)
  __shared__ __align__(16) short hbuf[16 * U_];
  // activated-gate exchange: [col 512][row 16] bf16
  __shared__ __align__(16) short gbuf[G4_ * 16];

  const int tid  = threadIdx.x;
  const int wave = tid >> 6;
  const int lane = tid & 63;
  const int lr   = lane & 15;   // A-row / D-col-in-tile
  const int lk   = lane >> 4;   // k sub-group 0..3
  const int b0   = blockIdx.x * 16;

  // ---- weight fragments (B-operand layout), loaded once, register-resident ----
  // B[k][col]: lane supplies col = nt*16 + lr, k = kc*32 + lk*8 + e. Same (lane,e)->k map
  // as the A side, so any hardware k-permutation cancels.
  s16x8 bWh[4][4], bWx[4][4];
#pragma unroll
  for (int ntl = 0; ntl < 4; ++ntl) {
    const int col = (wave * 4 + ntl) * 16 + lr;
#pragma unroll
    for (int kc = 0; kc < 4; ++kc) {
      s16x8 wh, wx;
#pragma unroll
      for (int e = 0; e < 8; ++e) {
        const int k = kc * 32 + lk * 8 + e;
        wh[e] = (short)f2bf(WH[k * G4_ + col]);
        wx[e] = (short)f2bf(WX[k * G4_ + col]);
      }
      bWh[ntl][kc] = wh;
      bWx[ntl][kc] = wx;
    }
  }

  // activation constants: waves 0-5 sigmoid, waves 6-7 tanh = 2*sigm(2x)-1 (branch-free)
  const bool issig = (wave < 6);
  const float aS1 = issig ? 1.0f : 2.0f;   // exp argument scale
  const float aS2 = issig ? 1.0f : 2.0f;   // output scale
  const float aS3 = issig ? 0.0f : -1.0f;  // output offset

  // ---- update-role state: thread (uu, rg) owns c/h for u=uu, rows rg*4..rg*4+3 ----
  const int uu = tid & 127;
  const int rg = tid >> 7;
  float c[4], hn[4];
#pragma unroll
  for (int r = 0; r < 4; ++r) {
    c[r]  = ST[(b0 + rg * 4 + r) * U_ + uu];
    hn[r] = ST[(B_ + b0 + rg * 4 + r) * U_ + uu];
  }
  { // apply mask m[0] and publish masked h
    f32x4 d = *(const f32x4*)&DN[b0 + rg * 4];
#pragma unroll
    for (int r = 0; r < 4; ++r) {
      const float m = 1.0f - d[r];
      c[r] *= m;
      const float hm = hn[r] * m;
      const int row = rg * 4 + r;
      const int sl  = (uu >> 3) ^ row;
      hbuf[row * U_ + sl * 8 + (uu & 7)] = (short)f2bf(hm);
    }
  }

  // ---- prologue: accA = x(0) @ Wx ----
  f32x4 accA[4], accB[4];
  {
    const float* xp = &X[(b0 + lr) * F_ + lk * 8];
    f32x4 xv0[4], xv1[4];
#pragma unroll
    for (int kc = 0; kc < 4; ++kc) {
      xv0[kc] = *(const f32x4*)&xp[kc * 32];
      xv1[kc] = *(const f32x4*)&xp[kc * 32 + 4];
    }
#pragma unroll
    for (int ntl = 0; ntl < 4; ++ntl) {
      f32x4 a = {0.f, 0.f, 0.f, 0.f};
#pragma unroll
      for (int kc = 0; kc < 4; ++kc)
        a = __builtin_amdgcn_mfma_f32_16x16x32_bf16(pack8(xv0[kc], xv1[kc]), bWx[ntl][kc], a, 0, 0, 0);
      accA[ntl] = a;
    }
  }
  __syncthreads();

  // accZ: holds x(t)@Wx on entry, becomes full z. accX: receives x(t+1)@Wx (ping-pong).
  auto step = [&](const int t, f32x4 (&accZ)[4], f32x4 (&accX)[4]) {
    const bool havex = (t + 1 < T_);
    // 1: issue next-step x loads early (HBM latency hides under MFMA/activation)
    f32x4 xv0[4], xv1[4];
    if (havex) {
      const float* xp = &X[((t + 1) * B_ + b0 + lr) * F_ + lk * 8];
#pragma unroll
      for (int kc = 0; kc < 4; ++kc) {
        xv0[kc] = *(const f32x4*)&xp[kc * 32];
        xv1[kc] = *(const f32x4*)&xp[kc * 32 + 4];
      }
    }
    // 2: h A-fragments from swizzled LDS (2-way conflict only)
    s16x8 ah[4];
#pragma unroll
    for (int kc = 0; kc < 4; ++kc) {
      const int sl = (kc * 4 + lk) ^ lr;
      ah[kc] = *(const s16x8*)&hbuf[lr * U_ + sl * 8];
    }
    // 3: z += h @ Wh
#pragma unroll
    for (int ntl = 0; ntl < 4; ++ntl) {
      f32x4 a = accZ[ntl];
#pragma unroll
      for (int kc = 0; kc < 4; ++kc)
        a = __builtin_amdgcn_mfma_f32_16x16x32_bf16(ah[kc], bWh[ntl][kc], a, 0, 0, 0);
      accZ[ntl] = a;
    }
    // 4: activate (wave-uniform gate), publish to gbuf
#pragma unroll
    for (int ntl = 0; ntl < 4; ++ntl) {
      s16x4 g;
#pragma unroll
      for (int r = 0; r < 4; ++r) {
        const float v  = accZ[ntl][r];
        const float e  = __expf(-aS1 * v);
        const float av = __fdividef(aS2, 1.0f + e) + aS3;
        g[r] = (short)f2bf(av);
      }
      const int col = wave * 64 + ntl * 16 + lr;
      *(s16x4*)&gbuf[col * 16 + lk * 4] = g;
    }
    // 5: independent x-part MFMAs for t+1 (fills pipe, off critical path)
    if (havex) {
      s16x8 xa[4];
#pragma unroll
      for (int kc = 0; kc < 4; ++kc) xa[kc] = pack8(xv0[kc], xv1[kc]);
#pragma unroll
      for (int ntl = 0; ntl < 4; ++ntl) {
        f32x4 a = {0.f, 0.f, 0.f, 0.f};
#pragma unroll
        for (int kc = 0; kc < 4; ++kc)
          a = __builtin_amdgcn_mfma_f32_16x16x32_bf16(xa[kc], bWx[ntl][kc], a, 0, 0, 0);
        accX[ntl] = a;
      }
    }
    __syncthreads();
    // 6: cell/hidden update in fp32 registers
    s16x4 gi = *(const s16x4*)&gbuf[(0 * U_ + uu) * 16 + rg * 4];
    s16x4 gf = *(const s16x4*)&gbuf[(1 * U_ + uu) * 16 + rg * 4];
    s16x4 go = *(const s16x4*)&gbuf[(2 * U_ + uu) * 16 + rg * 4];
    s16x4 gu = *(const s16x4*)&gbuf[(3 * U_ + uu) * 16 + rg * 4];
#pragma unroll
    for (int r = 0; r < 4; ++r) {
      const float iv = bf2f((unsigned short)gi[r]);
      const float fv = bf2f((unsigned short)gf[r]);
      const float ov = bf2f((unsigned short)go[r]);
      const float uv = bf2f((unsigned short)gu[r]);
      c[r]  = fv * c[r] + iv * uv;
      hn[r] = ov * tanh_fast(c[r]);
      OUT[((long)t * B_ + b0 + rg * 4 + r) * U_ + uu] = hn[r];  // coalesced per row
    }
    // 7: apply next step's episode mask, publish masked h
    if (havex) {
      f32x4 d = *(const f32x4*)&DN[(t + 1) * B_ + b0 + rg * 4];
#pragma unroll
      for (int r = 0; r < 4; ++r) {
        const float m = 1.0f - d[r];
        c[r] *= m;
        const float hm = hn[r] * m;
        const int row = rg * 4 + r;
        const int sl  = (uu >> 3) ^ row;
        hbuf[row * U_ + sl * 8 + (uu & 7)] = (short)f2bf(hm);
      }
    }
    __syncthreads();
  };

  for (int t = 0; t < T_; t += 2) {
    step(t,     accA, accB);
    step(t + 1, accB, accA);
  }

  // final carry (c, h) after step T-1, unmasked — matches reference's returned stack
  const long fb = (long)T_ * B_ * U_;
#pragma unroll
  for (int r = 0; r < 4; ++r) {
    OUT[fb + (long)(b0 + rg * 4 + r) * U_ + uu]            = c[r];
    OUT[fb + (long)B_ * U_ + (long)(b0 + rg * 4 + r) * U_ + uu] = hn[r];
  }
}

extern "C" void kernel_launch(void* const* d_in, const int* in_sizes, int n_in,
                              void* d_out, int out_size, void* d_ws, size_t ws_size,
                              hipStream_t stream) {
  const float* X  = (const float*)d_in[0];  // [T,B,F]
  const float* ST = (const float*)d_in[1];  // [2,B,U]
  const float* DN = (const float*)d_in[2];  // [T,B]
  const float* WX = (const float*)d_in[3];  // [F,4U]
  const float* WH = (const float*)d_in[4];  // [U,4U]
  // d_in[5] = bias, unused by the reference
  float* OUT = (float*)d_out;               // [T*B*U + 2*B*U]
  lstm_seq_kernel<<<dim3(16), dim3(512), 0, stream>>>(X, ST, DN, WX, WH, OUT);
}

// Round 2
// 1187.701 us; speedup vs baseline: 1.2951x; 1.2951x over previous
//
#include <hip/hip_runtime.h>

#define T_  512
#define B_  256
#define F_  128
#define U_  128
#define G4_ 512

using f32x4 = __attribute__((ext_vector_type(4))) float;
using s16x8 = __attribute__((ext_vector_type(8))) short;
using u32x4 = __attribute__((ext_vector_type(4))) unsigned int;

__device__ __forceinline__ unsigned fbits(float f) { return __builtin_bit_cast(unsigned, f); }

// fp32 -> bf16 round-to-nearest-even (h publish only)
__device__ __forceinline__ unsigned short f2bf(float f) {
  unsigned u = fbits(f);
  u += 0x7FFFu + ((u >> 16) & 1u);
  return (unsigned short)(u >> 16);
}
// pack 8 fp32 -> 8 bf16 by truncation (v_perm high halves); x operand only
__device__ __forceinline__ s16x8 pack8(f32x4 a, f32x4 b) {
  u32x4 w;
  w[0] = __builtin_amdgcn_perm(fbits(a[1]), fbits(a[0]), 0x07060302u);
  w[1] = __builtin_amdgcn_perm(fbits(a[3]), fbits(a[2]), 0x07060302u);
  w[2] = __builtin_amdgcn_perm(fbits(b[1]), fbits(b[0]), 0x07060302u);
  w[3] = __builtin_amdgcn_perm(fbits(b[3]), fbits(b[2]), 0x07060302u);
  return __builtin_bit_cast(s16x8, w);
}
// sigmoid: 1/(1+exp(-z)) — v_mul+v_exp+v_add+v_rcp, branch-free, saturates correctly
__device__ __forceinline__ float sigm(float z) {
  return __builtin_amdgcn_rcpf(1.0f + __expf(-z));
}
// tanh: 2/(1+exp(-2z)) - 1
__device__ __forceinline__ float tanh_fast(float z) {
  return 2.0f * __builtin_amdgcn_rcpf(1.0f + __expf(-2.0f * z)) - 1.0f;
}

__global__ __launch_bounds__(512, 1)
void lstm_seq_kernel(const float* __restrict__ X, const float* __restrict__ ST,
                     const float* __restrict__ DN, const float* __restrict__ WX,
                     const float* __restrict__ WH, float* __restrict__ OUT)
{
  // h exchange, double-buffered: [buf 2][row 16][u 128] bf16, XOR-swizzled 8-elem slots
  __shared__ __align__(16) short hbuf[2][16 * U_];

  const int tid  = threadIdx.x;
  const int w    = tid >> 6;     // wave 0..7
  const int lane = tid & 63;
  const int lr   = lane & 15;    // A-row / D-col-in-tile
  const int lk   = lane >> 4;    // k sub-group 0..3 / D-row-group
  const int b0   = blockIdx.x * 16;
  const int row0 = lk * 4;       // this thread's 4 batch rows (within tile)
  const int uu   = w * 16 + lr;  // this thread's unit index 0..127

  // ---- weight fragments: wave w owns N-tiles {w, 8+w, 16+w, 24+w} => acc[g] is
  // gate g (cols g*128 + w*16 + lr). All 4 gates of unit uu live in THIS thread.
  s16x8 bWh[4][4], bWx[4][4];
#pragma unroll
  for (int g = 0; g < 4; ++g) {
    const int col = g * 128 + uu;
#pragma unroll
    for (int kc = 0; kc < 4; ++kc) {
      s16x8 wh, wx;
#pragma unroll
      for (int e = 0; e < 8; ++e) {
        const int k = kc * 32 + lk * 8 + e;
        wh[e] = (short)f2bf(WH[k * G4_ + col]);
        wx[e] = (short)f2bf(WX[k * G4_ + col]);
      }
      bWh[g][kc] = wh;
      bWx[g][kc] = wx;
    }
  }

  // ---- state: thread owns c/h for (rows b0+row0..+3, unit uu), fp32 ----
  float c[4], hn[4];
#pragma unroll
  for (int r = 0; r < 4; ++r) {
    c[r]  = ST[(b0 + row0 + r) * U_ + uu];
    hn[r] = ST[(B_ + b0 + row0 + r) * U_ + uu];
  }
  { // apply mask m(0), publish masked h(0) to hbuf[0]
    f32x4 d = *(const f32x4*)&DN[b0 + row0];
#pragma unroll
    for (int r = 0; r < 4; ++r) {
      const float m = 1.0f - d[r];
      c[r] *= m;
      const int row = row0 + r;
      const int sl  = (uu >> 3) ^ row;
      hbuf[0][row * U_ + sl * 8 + (uu & 7)] = (short)f2bf(hn[r] * m);
    }
  }

  // ---- prologue: accA = x(0) @ Wx ----
  f32x4 accA[4], accB[4];
  {
    const float* xp = &X[(b0 + lr) * F_ + lk * 8];
    s16x8 xa[4];
#pragma unroll
    for (int kc = 0; kc < 4; ++kc)
      xa[kc] = pack8(*(const f32x4*)&xp[kc * 32], *(const f32x4*)&xp[kc * 32 + 4]);
#pragma unroll
    for (int g = 0; g < 4; ++g) {
      f32x4 a = {0.f, 0.f, 0.f, 0.f};
#pragma unroll
      for (int kc = 0; kc < 4; ++kc)
        a = __builtin_amdgcn_mfma_f32_16x16x32_bf16(xa[kc], bWx[g][kc], a, 0, 0, 0);
      accA[g] = a;
    }
  }
  __syncthreads();

  // running pointers (avoid per-step address recompute)
  const float* xnext = &X[(B_ + b0 + lr) * F_ + lk * 8];  // x(t+1), starts at t=1
  const float* dnext = &DN[B_ + b0 + row0];               // dones(t+1)
  float*       outp  = &OUT[(long)(b0 + row0) * U_ + uu]; // h(t) out, advance by B*U

  // one barrier per step; hbuf ping-pongs on t&1
  auto step = [&](const int p, const bool havex, f32x4 (&accZ)[4], f32x4 (&accX)[4]) {
    // 1: issue next-step x + dones loads early (hide HBM/L3 latency under MFMA+VALU)
    f32x4 xv0[4], xv1[4], d;
    if (havex) {
#pragma unroll
      for (int kc = 0; kc < 4; ++kc) {
        xv0[kc] = *(const f32x4*)(xnext + kc * 32);
        xv1[kc] = *(const f32x4*)(xnext + kc * 32 + 4);
      }
      d = *(const f32x4*)dnext;
    }
    // 2: h A-fragments from swizzled LDS
    s16x8 ah[4];
#pragma unroll
    for (int kc = 0; kc < 4; ++kc) {
      const int sl = (kc * 4 + lk) ^ lr;
      ah[kc] = *(const s16x8*)&hbuf[p][lr * U_ + sl * 8];
    }
    // 3: z = accX + h @ Wh  (acc[g] = gate g for unit uu, rows row0..+3)
#pragma unroll
    for (int g = 0; g < 4; ++g) {
      f32x4 a = accZ[g];
#pragma unroll
      for (int kc = 0; kc < 4; ++kc)
        a = __builtin_amdgcn_mfma_f32_16x16x32_bf16(ah[kc], bWh[g][kc], a, 0, 0, 0);
      accZ[g] = a;
    }
    // 4: in-register activations (fp32) + cell/hidden update + output store
#pragma unroll
    for (int r = 0; r < 4; ++r) {
      const float gi = sigm(accZ[0][r]);
      const float gf = sigm(accZ[1][r]);
      const float go = sigm(accZ[2][r]);
      const float gu = tanh_fast(accZ[3][r]);
      const float cn = gf * c[r] + gi * gu;
      const float h  = go * tanh_fast(cn);
      c[r]  = cn;
      hn[r] = h;
      outp[r * U_] = h;
    }
    // 5: independent x(t+1)@Wx on the MFMA pipe (off critical path)
    if (havex) {
      s16x8 xa[4];
#pragma unroll
      for (int kc = 0; kc < 4; ++kc) xa[kc] = pack8(xv0[kc], xv1[kc]);
#pragma unroll
      for (int g = 0; g < 4; ++g) {
        f32x4 a = {0.f, 0.f, 0.f, 0.f};
#pragma unroll
        for (int kc = 0; kc < 4; ++kc)
          a = __builtin_amdgcn_mfma_f32_16x16x32_bf16(xa[kc], bWx[g][kc], a, 0, 0, 0);
        accX[g] = a;
      }
      // 6: apply mask m(t+1), publish masked h(t+1) to the other buffer
#pragma unroll
      for (int r = 0; r < 4; ++r) {
        const float m = 1.0f - d[r];
        c[r] *= m;
        const int row = row0 + r;
        const int sl  = (uu >> 3) ^ row;
        hbuf[p ^ 1][row * U_ + sl * 8 + (uu & 7)] = (short)f2bf(hn[r] * m);
      }
    }
    __syncthreads();
  };

  for (int t = 0; t < T_; t += 2) {
    step(0, true, accA, accB);
    xnext += B_ * F_; dnext += B_; outp += B_ * U_;
    step(1, (t + 2) < T_, accB, accA);
    xnext += B_ * F_; dnext += B_; outp += B_ * U_;
  }

  // final carry (c, h) after step T-1, unmasked
  const long fb = (long)T_ * B_ * U_;
#pragma unroll
  for (int r = 0; r < 4; ++r) {
    OUT[fb + (long)(b0 + row0 + r) * U_ + uu]                 = c[r];
    OUT[fb + (long)B_ * U_ + (long)(b0 + row0 + r) * U_ + uu] = hn[r];
  }
}

extern "C" void kernel_launch(void* const* d_in, const int* in_sizes, int n_in,
                              void* d_out, int out_size, void* d_ws, size_t ws_size,
                              hipStream_t stream) {
  const float* X  = (const float*)d_in[0];  // [T,B,F]
  const float* ST = (const float*)d_in[1];  // [2,B,U]
  const float* DN = (const float*)d_in[2];  // [T,B]
  const float* WX = (const float*)d_in[3];  // [F,4U]
  const float* WH = (const float*)d_in[4];  // [U,4U]
  float* OUT = (float*)d_out;               // [T*B*U + 2*B*U]
  lstm_seq_kernel<<<dim3(16), dim3(512), 0, stream>>>(X, ST, DN, WX, WH, OUT);
}

// Round 3
// 959.427 us; speedup vs baseline: 1.6033x; 1.2379x over previous
//
#include <hip/hip_runtime.h>

#define T_  512
#define B_  256
#define F_  128
#define U_  128
#define G4_ 512

using f32x4 = __attribute__((ext_vector_type(4))) float;
using s16x8 = __attribute__((ext_vector_type(8))) short;
using u32x4 = __attribute__((ext_vector_type(4))) unsigned int;

__device__ __forceinline__ unsigned fbits(float f) { return __builtin_bit_cast(unsigned, f); }

// scalar RNE fp32->bf16 (preamble only)
__device__ __forceinline__ unsigned short f2bf(float f) {
  unsigned u = fbits(f);
  u += 0x7FFFu + ((u >> 16) & 1u);
  return (unsigned short)(u >> 16);
}
// hardware RNE pack: low16 = bf16(lo), high16 = bf16(hi)
__device__ __forceinline__ unsigned cvt_pk_bf16(float lo, float hi) {
  unsigned r;
  asm("v_cvt_pk_bf16_f32 %0, %1, %2" : "=v"(r) : "v"(lo), "v"(hi));
  return r;
}
__device__ __forceinline__ s16x8 pack8(f32x4 a, f32x4 b) {
  u32x4 w;
  w[0] = cvt_pk_bf16(a[0], a[1]);
  w[1] = cvt_pk_bf16(a[2], a[3]);
  w[2] = cvt_pk_bf16(b[0], b[1]);
  w[3] = cvt_pk_bf16(b[2], b[3]);
  return __builtin_bit_cast(s16x8, w);
}
// barrier that only waits on LDS ops (hbuf) — global stores / prefetch loads
// stay in flight across steps (no vmcnt(0)/expcnt(0) drain per step).
__device__ __forceinline__ void sync_lds() {
  asm volatile("s_waitcnt lgkmcnt(0)\n\ts_barrier" ::: "memory");
}

__global__ __launch_bounds__(512, 1)
void lstm_seq_kernel(const float* __restrict__ X, const float* __restrict__ ST,
                     const float* __restrict__ DN, const float* __restrict__ WX,
                     const float* __restrict__ WH, float* __restrict__ OUT)
{
  __shared__ __align__(16) short hbuf[2][16 * U_];  // XOR-swizzled, double-buffered

  const int tid  = threadIdx.x;
  const int w    = tid >> 6;
  const int lane = tid & 63;
  const int lr   = lane & 15;
  const int lk   = lane >> 4;
  const int b0   = blockIdx.x * 16;
  const int row0 = lk * 4;
  const int uu   = w * 16 + lr;

  // thread-constant offsets (uniform stepped bases below -> saddr-form loads)
  const int xoff = (b0 + lr) * F_ + lk * 8;
  const int doff = b0 + row0;
  const int ooff = (b0 + row0) * U_ + uu;

  // ---- weights: wave w owns N-tiles {w,8+w,16+w,24+w} => acc[g] = gate g of unit uu
  s16x8 bWh[4][4], bWx[4][4];
#pragma unroll
  for (int g = 0; g < 4; ++g) {
    const int col = g * 128 + uu;
#pragma unroll
    for (int kc = 0; kc < 4; ++kc) {
      s16x8 wh, wx;
#pragma unroll
      for (int e = 0; e < 8; ++e) {
        const int k = kc * 32 + lk * 8 + e;
        wh[e] = (short)f2bf(WH[k * G4_ + col]);
        wx[e] = (short)f2bf(WX[k * G4_ + col]);
      }
      bWh[g][kc] = wh;
      bWx[g][kc] = wx;
    }
  }

  // ---- fp32 state ----
  float c[4], hn[4];
#pragma unroll
  for (int r = 0; r < 4; ++r) {
    c[r]  = ST[(b0 + row0 + r) * U_ + uu];
    hn[r] = ST[(B_ + b0 + row0 + r) * U_ + uu];
  }
  { // mask m(0), publish masked h(0)
    f32x4 d = *(const f32x4*)&DN[doff];
#pragma unroll
    for (int r = 0; r < 4; ++r) {
      const float m = 1.0f - d[r];
      c[r] *= m;
      const int row = row0 + r;
      const int sl  = (uu >> 3) ^ row;
      hbuf[0][row * U_ + sl * 8 + (uu & 7)] = (short)cvt_pk_bf16(hn[r] * m, 0.f);
    }
  }

  // persistent prefetch registers: xv = x(t+1) data, dv = d(t+1)
  f32x4 xv0[4], xv1[4], dv;
  f32x4 accA[4], accB[4];

  // ---- prologue: accA = x(0)@Wx; issue x(1), d(1) ----
  {
    const float* xp = X + xoff;
    s16x8 xa[4];
#pragma unroll
    for (int kc = 0; kc < 4; ++kc)
      xa[kc] = pack8(*(const f32x4*)(xp + kc * 32), *(const f32x4*)(xp + kc * 32 + 4));
#pragma unroll
    for (int g = 0; g < 4; ++g) {
      f32x4 a = {0.f, 0.f, 0.f, 0.f};
#pragma unroll
      for (int kc = 0; kc < 4; ++kc)
        a = __builtin_amdgcn_mfma_f32_16x16x32_bf16(xa[kc], bWx[g][kc], a, 0, 0, 0);
      accA[g] = a;
    }
#pragma unroll
    for (int kc = 0; kc < 4; ++kc) {
      xv0[kc] = *(const f32x4*)(X + B_ * F_ + xoff + kc * 32);
      xv1[kc] = *(const f32x4*)(X + B_ * F_ + xoff + kc * 32 + 4);
    }
    dv = *(const f32x4*)(DN + B_ + doff);
  }
  sync_lds();

  // uniform stepped bases: Xt -> x(t+2), DNt -> d(t+2), Ot -> h(t) out
  const float* Xt  = X + 2 * B_ * F_;
  const float* DNt = DN + 2 * B_;
  float*       Ot  = OUT;

  auto step = [&](const int p, const bool act_x, const bool pre_x,
                  f32x4 (&accZ)[4], f32x4 (&accX)[4]) {
    // a) h fragments first (LDS latency starts counting immediately)
    s16x8 ah[4];
#pragma unroll
    for (int kc = 0; kc < 4; ++kc) {
      const int sl = (kc * 4 + lk) ^ lr;
      ah[kc] = *(const s16x8*)&hbuf[p][lr * U_ + sl * 8];
    }
    // b) z = zx + h @ Wh
#pragma unroll
    for (int g = 0; g < 4; ++g) {
      f32x4 a = accZ[g];
#pragma unroll
      for (int kc = 0; kc < 4; ++kc)
        a = __builtin_amdgcn_mfma_f32_16x16x32_bf16(ah[kc], bWh[g][kc], a, 0, 0, 0);
      accZ[g] = a;
    }
    // c) activations (combined denominators: 5 exp + 3 rcp), update, output
#pragma unroll
    for (int r = 0; r < 4; ++r) {
      const float eA = __expf(-accZ[0][r]);          // e^-zi
      const float eB = __expf(-2.0f * accZ[3][r]);   // e^-2zu
      const float eC = __expf(-accZ[1][r]);          // e^-zf
      const float eD = __expf(-accZ[2][r]);          // e^-zo
      const float iu = (1.0f - eB) * __builtin_amdgcn_rcpf((1.0f + eA) * (1.0f + eB));
      const float fg = __builtin_amdgcn_rcpf(1.0f + eC);
      const float cn = fmaf(fg, c[r], iu);
      const float ce = fminf(fmaxf(cn, -30.0f), 30.0f);
      const float eE = __expf(-2.0f * ce);
      const float h  = (1.0f - eE) * __builtin_amdgcn_rcpf((1.0f + eD) * (1.0f + eE));
      c[r]  = cn;
      hn[r] = h;
      Ot[ooff + r * U_] = h;
    }
    // d) x(t+1)@Wx from prefetched xv (consumes xv -> regs free for next issue)
    if (act_x) {
      s16x8 xa[4];
#pragma unroll
      for (int kc = 0; kc < 4; ++kc) xa[kc] = pack8(xv0[kc], xv1[kc]);
#pragma unroll
      for (int g = 0; g < 4; ++g) {
        f32x4 a = {0.f, 0.f, 0.f, 0.f};
#pragma unroll
        for (int kc = 0; kc < 4; ++kc)
          a = __builtin_amdgcn_mfma_f32_16x16x32_bf16(xa[kc], bWx[g][kc], a, 0, 0, 0);
        accX[g] = a;
      }
    }
    // e) issue x(t+2)/d(t+2) now -> full-step latency cover, same registers
    f32x4 dcur = dv;  // d(t+1)
    if (pre_x) {
#pragma unroll
      for (int kc = 0; kc < 4; ++kc) {
        xv0[kc] = *(const f32x4*)(Xt + xoff + kc * 32);
        xv1[kc] = *(const f32x4*)(Xt + xoff + kc * 32 + 4);
      }
      dv = *(const f32x4*)(DNt + doff);
    }
    // f) mask m(t+1), publish masked h(t+1)
    if (act_x) {
#pragma unroll
      for (int r = 0; r < 4; ++r) {
        const float m = 1.0f - dcur[r];
        c[r] *= m;
        const int row = row0 + r;
        const int sl  = (uu >> 3) ^ row;
        hbuf[p ^ 1][row * U_ + sl * 8 + (uu & 7)] = (short)cvt_pk_bf16(hn[r] * m, 0.f);
      }
    }
    // g) LDS-only barrier
    sync_lds();
  };

  for (int t = 0; t < T_; t += 2) {
    step(0, true, t + 2 < T_, accA, accB);
    Xt += B_ * F_; DNt += B_; Ot += B_ * U_;
    step(1, t + 2 < T_, t + 3 < T_, accB, accA);
    Xt += B_ * F_; DNt += B_; Ot += B_ * U_;
  }

  // final carry (c, h) after step T-1, unmasked
  const long fb = (long)T_ * B_ * U_;
#pragma unroll
  for (int r = 0; r < 4; ++r) {
    OUT[fb + (long)(b0 + row0 + r) * U_ + uu]                 = c[r];
    OUT[fb + (long)B_ * U_ + (long)(b0 + row0 + r) * U_ + uu] = hn[r];
  }
}

extern "C" void kernel_launch(void* const* d_in, const int* in_sizes, int n_in,
                              void* d_out, int out_size, void* d_ws, size_t ws_size,
                              hipStream_t stream) {
  const float* X  = (const float*)d_in[0];  // [T,B,F]
  const float* ST = (const float*)d_in[1];  // [2,B,U]
  const float* DN = (const float*)d_in[2];  // [T,B]
  const float* WX = (const float*)d_in[3];  // [F,4U]
  const float* WH = (const float*)d_in[4];  // [U,4U]
  float* OUT = (float*)d_out;               // [T*B*U + 2*B*U]
  lstm_seq_kernel<<<dim3(16), dim3(512), 0, stream>>>(X, ST, DN, WX, WH, OUT);
}

// Round 4
// 814.313 us; speedup vs baseline: 1.8890x; 1.1782x over previous
//
#include <hip/hip_runtime.h>

#define T_  512
#define B_  256
#define F_  128
#define U_  128
#define G4_ 512
#define L2E 1.4426950408889634f
#define ZSTRIDE (16 * 512 * 16)                      // zx floats per timestep
#define ZX_BYTES ((size_t)T_ * B_ * G4_ * 4)         // 268435456

using f32x4 = __attribute__((ext_vector_type(4))) float;
using s16x8 = __attribute__((ext_vector_type(8))) short;
using u32x4 = __attribute__((ext_vector_type(4))) unsigned int;

__device__ __forceinline__ unsigned fbits(float f) { return __builtin_bit_cast(unsigned, f); }

// scalar RNE fp32->bf16 (weight preamble only)
__device__ __forceinline__ unsigned short f2bf(float f) {
  unsigned u = fbits(f);
  u += 0x7FFFu + ((u >> 16) & 1u);
  return (unsigned short)(u >> 16);
}
// hardware RNE pack: low16 = bf16(lo), high16 = bf16(hi)
__device__ __forceinline__ unsigned cvt_pk_bf16(float lo, float hi) {
  unsigned r;
  asm("v_cvt_pk_bf16_f32 %0, %1, %2" : "=v"(r) : "v"(lo), "v"(hi));
  return r;
}
__device__ __forceinline__ s16x8 pack8(f32x4 a, f32x4 b) {
  u32x4 w;
  w[0] = cvt_pk_bf16(a[0], a[1]);
  w[1] = cvt_pk_bf16(a[2], a[3]);
  w[2] = cvt_pk_bf16(b[0], b[1]);
  w[3] = cvt_pk_bf16(b[2], b[3]);
  return __builtin_bit_cast(s16x8, w);
}
// barrier that only waits on LDS ops — global loads/stores stay in flight
__device__ __forceinline__ void sync_lds() {
  asm volatile("s_waitcnt lgkmcnt(0)\n\ts_barrier" ::: "memory");
}

// ============ kernel 1: zx = X @ (Wx * gate_scale), fragment-layout output ============
// grid 256 x 512thr. Block b computes row-groups G = b*32 .. b*32+31 (16 rows each).
// Output layout: ZX[((G*8 + wave)*64 + lane)*16 + g*4 + r]  == MFMA C/D fragment order.
__global__ __launch_bounds__(512, 1)
void zx_gemm_kernel(const float* __restrict__ X, const float* __restrict__ WX,
                    float* __restrict__ ZX)
{
  const int tid  = threadIdx.x;
  const int w    = tid >> 6;
  const int lane = tid & 63;
  const int lr   = lane & 15;
  const int lk   = lane >> 4;

  s16x8 bWx[4][4];
#pragma unroll
  for (int g = 0; g < 4; ++g) {
    const float scl = (g == 3) ? 2.0f * L2E : L2E;   // u-gate carries tanh's 2x
    const int col = g * 128 + w * 16 + lr;
#pragma unroll
    for (int kc = 0; kc < 4; ++kc) {
      s16x8 wx;
#pragma unroll
      for (int e = 0; e < 8; ++e) {
        const int k = kc * 32 + lk * 8 + e;
        wx[e] = (short)f2bf(WX[k * G4_ + col] * scl);
      }
      bWx[g][kc] = wx;
    }
  }

  const int G0 = blockIdx.x * 32;
  const float* xp = X + (size_t)(G0 * 16 + lr) * F_ + lk * 8;
  float*       zp = ZX + ((size_t)(G0 * 8 + w) * 64 + lane) * 16;

  for (int grp = 0; grp < 32; ++grp) {
    s16x8 xa[4];
#pragma unroll
    for (int kc = 0; kc < 4; ++kc)
      xa[kc] = pack8(*(const f32x4*)(xp + kc * 32), *(const f32x4*)(xp + kc * 32 + 4));
#pragma unroll
    for (int g = 0; g < 4; ++g) {
      f32x4 a = {0.f, 0.f, 0.f, 0.f};
#pragma unroll
      for (int kc = 0; kc < 4; ++kc)
        a = __builtin_amdgcn_mfma_f32_16x16x32_bf16(xa[kc], bWx[g][kc], a, 0, 0, 0);
      *(f32x4*)(zp + g * 4) = a;
    }
    xp += 16 * F_;
    zp += 8 * 64 * 16;
  }
}

// ============ kernel 2: recurrent scan consuming precomputed zx ============
__global__ __launch_bounds__(512, 1)
void lstm_zx_kernel(const float* __restrict__ ZX, const float* __restrict__ ST,
                    const float* __restrict__ DN, const float* __restrict__ WH,
                    float* __restrict__ OUT)
{
  __shared__ __align__(16) short hbuf[2][16 * U_];  // XOR-swizzled, double-buffered

  const int tid  = threadIdx.x;
  const int w    = tid >> 6;
  const int lane = tid & 63;
  const int lr   = lane & 15;
  const int lk   = lane >> 4;
  const int b0   = blockIdx.x * 16;
  const int row0 = lk * 4;
  const int uu   = w * 16 + lr;

  const int doff = b0 + row0;
  const int ooff = (b0 + row0) * U_ + uu;

  // Wh, pre-scaled per gate (log2e; 2*log2e for u)
  s16x8 bWh[4][4];
#pragma unroll
  for (int g = 0; g < 4; ++g) {
    const float scl = (g == 3) ? 2.0f * L2E : L2E;
    const int col = g * 128 + uu;
#pragma unroll
    for (int kc = 0; kc < 4; ++kc) {
      s16x8 wh;
#pragma unroll
      for (int e = 0; e < 8; ++e) {
        const int k = kc * 32 + lk * 8 + e;
        wh[e] = (short)f2bf(WH[k * G4_ + col] * scl);
      }
      bWh[g][kc] = wh;
    }
  }

  // fp32 state
  float c[4], hn[4];
#pragma unroll
  for (int r = 0; r < 4; ++r) {
    c[r]  = ST[(b0 + row0 + r) * U_ + uu];
    hn[r] = ST[(B_ + b0 + row0 + r) * U_ + uu];
  }
  { // mask m(0), publish masked h(0)
    f32x4 d = *(const f32x4*)&DN[doff];
#pragma unroll
    for (int r = 0; r < 4; ++r) {
      const float m = 1.0f - d[r];
      c[r] *= m;
      const int row = row0 + r;
      const int sl  = (uu >> 3) ^ row;
      hbuf[0][row * U_ + sl * 8 + (uu & 7)] = (short)cvt_pk_bf16(hn[r] * m, 0.f);
    }
  }

  // zx prefetch ping-pong: zxA = zx(t even), zxB = zx(t odd); dv = d(t+1)
  const float* zbase = ZX + ((size_t)blockIdx.x * 512 + tid) * 16;
  f32x4 zxA[4], zxB[4], dv;
#pragma unroll
  for (int g = 0; g < 4; ++g) zxA[g] = *(const f32x4*)(zbase + g * 4);
#pragma unroll
  for (int g = 0; g < 4; ++g) zxB[g] = *(const f32x4*)(zbase + ZSTRIDE + g * 4);
  dv = *(const f32x4*)(DN + B_ + doff);
  sync_lds();  // h(0) visible

  const float* Zt  = zbase + 2 * (size_t)ZSTRIDE;  // zx(t+2)
  const float* DNt = DN + 2 * B_;                  // d(t+2)
  float*       Ot  = OUT;

  auto step = [&](const int p, const bool pub, const bool pre, f32x4 (&zxC)[4]) {
    // a) h(t) fragments from swizzled LDS
    s16x8 ah[4];
#pragma unroll
    for (int kc = 0; kc < 4; ++kc) {
      const int sl = (kc * 4 + lk) ^ lr;
      ah[kc] = *(const s16x8*)&hbuf[p][lr * U_ + sl * 8];
    }
    // b) z = zx + h @ Wh  (zx prefetched regs ARE the C-init)
    f32x4 az[4];
#pragma unroll
    for (int g = 0; g < 4; ++g) {
      f32x4 a = zxC[g];
#pragma unroll
      for (int kc = 0; kc < 4; ++kc)
        a = __builtin_amdgcn_mfma_f32_16x16x32_bf16(ah[kc], bWh[g][kc], a, 0, 0, 0);
      az[g] = a;
    }
    // c) refill zxC with zx(t+2) (WAR resolved: first MFMA of each chain consumed it)
    if (pre) {
#pragma unroll
      for (int g = 0; g < 4; ++g) zxC[g] = *(const f32x4*)(Zt + g * 4);
    }
    // d) activations: z pre-scaled by log2e -> bare v_exp ops
#pragma unroll
    for (int r = 0; r < 4; ++r) {
      const float eA = exp2f(-az[0][r]);            // sigmoid(zi) denom term
      const float eC = exp2f(-az[1][r]);            // sigmoid(zf)
      const float eD = exp2f(-az[2][r]);            // sigmoid(zo)
      const float eB = exp2f(-az[3][r]);            // tanh(zu): u-gate pre-scaled 2x
      const float iu = (1.0f - eB) * __builtin_amdgcn_rcpf((1.0f + eA) * (1.0f + eB));
      const float fg = __builtin_amdgcn_rcpf(1.0f + eC);
      const float cn = fmaf(fg, c[r], iu);
      const float ce = fminf(fmaxf(cn, -15.0f), 15.0f);
      const float eE = exp2f(-2.0f * L2E * ce);
      const float h  = (1.0f - eE) * __builtin_amdgcn_rcpf((1.0f + eD) * (1.0f + eE));
      c[r]  = cn;
      hn[r] = h;
      Ot[ooff + r * U_] = h;
    }
    // e) dones for t+1 (held), issue d(t+2)
    f32x4 dcur = dv;
    if (pre) dv = *(const f32x4*)(DNt + doff);
    // f) mask m(t+1), publish masked h(t+1)
    if (pub) {
#pragma unroll
      for (int r = 0; r < 4; ++r) {
        const float m = 1.0f - dcur[r];
        c[r] *= m;
        const int row = row0 + r;
        const int sl  = (uu >> 3) ^ row;
        hbuf[p ^ 1][row * U_ + sl * 8 + (uu & 7)] = (short)cvt_pk_bf16(hn[r] * m, 0.f);
      }
    }
    sync_lds();
  };

  for (int t = 0; t < T_; t += 2) {
    step(0, true, t + 2 < T_, zxA);
    Zt += ZSTRIDE; DNt += B_; Ot += B_ * U_;
    step(1, t + 2 < T_, t + 3 < T_, zxB);
    Zt += ZSTRIDE; DNt += B_; Ot += B_ * U_;
  }

  const long fb = (long)T_ * B_ * U_;
#pragma unroll
  for (int r = 0; r < 4; ++r) {
    OUT[fb + (long)(b0 + row0 + r) * U_ + uu]                 = c[r];
    OUT[fb + (long)B_ * U_ + (long)(b0 + row0 + r) * U_ + uu] = hn[r];
  }
}

// ============ fallback (R3 kernel verbatim): used when ws is too small ============
__global__ __launch_bounds__(512, 1)
void lstm_fb_kernel(const float* __restrict__ X, const float* __restrict__ ST,
                    const float* __restrict__ DN, const float* __restrict__ WX,
                    const float* __restrict__ WH, float* __restrict__ OUT)
{
  __shared__ __align__(16) short hbuf[2][16 * U_];

  const int tid  = threadIdx.x;
  const int w    = tid >> 6;
  const int lane = tid & 63;
  const int lr   = lane & 15;
  const int lk   = lane >> 4;
  const int b0   = blockIdx.x * 16;
  const int row0 = lk * 4;
  const int uu   = w * 16 + lr;

  const int xoff = (b0 + lr) * F_ + lk * 8;
  const int doff = b0 + row0;
  const int ooff = (b0 + row0) * U_ + uu;

  s16x8 bWh[4][4], bWx[4][4];
#pragma unroll
  for (int g = 0; g < 4; ++g) {
    const int col = g * 128 + uu;
#pragma unroll
    for (int kc = 0; kc < 4; ++kc) {
      s16x8 wh, wx;
#pragma unroll
      for (int e = 0; e < 8; ++e) {
        const int k = kc * 32 + lk * 8 + e;
        wh[e] = (short)f2bf(WH[k * G4_ + col]);
        wx[e] = (short)f2bf(WX[k * G4_ + col]);
      }
      bWh[g][kc] = wh;
      bWx[g][kc] = wx;
    }
  }

  float c[4], hn[4];
#pragma unroll
  for (int r = 0; r < 4; ++r) {
    c[r]  = ST[(b0 + row0 + r) * U_ + uu];
    hn[r] = ST[(B_ + b0 + row0 + r) * U_ + uu];
  }
  {
    f32x4 d = *(const f32x4*)&DN[doff];
#pragma unroll
    for (int r = 0; r < 4; ++r) {
      const float m = 1.0f - d[r];
      c[r] *= m;
      const int row = row0 + r;
      const int sl  = (uu >> 3) ^ row;
      hbuf[0][row * U_ + sl * 8 + (uu & 7)] = (short)cvt_pk_bf16(hn[r] * m, 0.f);
    }
  }

  f32x4 xv0[4], xv1[4], dv;
  f32x4 accA[4], accB[4];
  {
    const float* xp = X + xoff;
    s16x8 xa[4];
#pragma unroll
    for (int kc = 0; kc < 4; ++kc)
      xa[kc] = pack8(*(const f32x4*)(xp + kc * 32), *(const f32x4*)(xp + kc * 32 + 4));
#pragma unroll
    for (int g = 0; g < 4; ++g) {
      f32x4 a = {0.f, 0.f, 0.f, 0.f};
#pragma unroll
      for (int kc = 0; kc < 4; ++kc)
        a = __builtin_amdgcn_mfma_f32_16x16x32_bf16(xa[kc], bWx[g][kc], a, 0, 0, 0);
      accA[g] = a;
    }
#pragma unroll
    for (int kc = 0; kc < 4; ++kc) {
      xv0[kc] = *(const f32x4*)(X + B_ * F_ + xoff + kc * 32);
      xv1[kc] = *(const f32x4*)(X + B_ * F_ + xoff + kc * 32 + 4);
    }
    dv = *(const f32x4*)(DN + B_ + doff);
  }
  sync_lds();

  const float* Xt  = X + 2 * B_ * F_;
  const float* DNt = DN + 2 * B_;
  float*       Ot  = OUT;

  auto step = [&](const int p, const bool act_x, const bool pre_x,
                  f32x4 (&accZ)[4], f32x4 (&accX)[4]) {
    s16x8 ah[4];
#pragma unroll
    for (int kc = 0; kc < 4; ++kc) {
      const int sl = (kc * 4 + lk) ^ lr;
      ah[kc] = *(const s16x8*)&hbuf[p][lr * U_ + sl * 8];
    }
#pragma unroll
    for (int g = 0; g < 4; ++g) {
      f32x4 a = accZ[g];
#pragma unroll
      for (int kc = 0; kc < 4; ++kc)
        a = __builtin_amdgcn_mfma_f32_16x16x32_bf16(ah[kc], bWh[g][kc], a, 0, 0, 0);
      accZ[g] = a;
    }
#pragma unroll
    for (int r = 0; r < 4; ++r) {
      const float eA = __expf(-accZ[0][r]);
      const float eB = __expf(-2.0f * accZ[3][r]);
      const float eC = __expf(-accZ[1][r]);
      const float eD = __expf(-accZ[2][r]);
      const float iu = (1.0f - eB) * __builtin_amdgcn_rcpf((1.0f + eA) * (1.0f + eB));
      const float fg = __builtin_amdgcn_rcpf(1.0f + eC);
      const float cn = fmaf(fg, c[r], iu);
      const float ce = fminf(fmaxf(cn, -30.0f), 30.0f);
      const float eE = __expf(-2.0f * ce);
      const float h  = (1.0f - eE) * __builtin_amdgcn_rcpf((1.0f + eD) * (1.0f + eE));
      c[r]  = cn;
      hn[r] = h;
      Ot[ooff + r * U_] = h;
    }
    if (act_x) {
      s16x8 xa[4];
#pragma unroll
      for (int kc = 0; kc < 4; ++kc) xa[kc] = pack8(xv0[kc], xv1[kc]);
#pragma unroll
      for (int g = 0; g < 4; ++g) {
        f32x4 a = {0.f, 0.f, 0.f, 0.f};
#pragma unroll
        for (int kc = 0; kc < 4; ++kc)
          a = __builtin_amdgcn_mfma_f32_16x16x32_bf16(xa[kc], bWx[g][kc], a, 0, 0, 0);
        accX[g] = a;
      }
    }
    f32x4 dcur = dv;
    if (pre_x) {
#pragma unroll
      for (int kc = 0; kc < 4; ++kc) {
        xv0[kc] = *(const f32x4*)(Xt + xoff + kc * 32);
        xv1[kc] = *(const f32x4*)(Xt + xoff + kc * 32 + 4);
      }
      dv = *(const f32x4*)(DNt + doff);
    }
    if (act_x) {
#pragma unroll
      for (int r = 0; r < 4; ++r) {
        const float m = 1.0f - dcur[r];
        c[r] *= m;
        const int row = row0 + r;
        const int sl  = (uu >> 3) ^ row;
        hbuf[p ^ 1][row * U_ + sl * 8 + (uu & 7)] = (short)cvt_pk_bf16(hn[r] * m, 0.f);
      }
    }
    sync_lds();
  };

  for (int t = 0; t < T_; t += 2) {
    step(0, true, t + 2 < T_, accA, accB);
    Xt += B_ * F_; DNt += B_; Ot += B_ * U_;
    step(1, t + 2 < T_, t + 3 < T_, accB, accA);
    Xt += B_ * F_; DNt += B_; Ot += B_ * U_;
  }

  const long fb = (long)T_ * B_ * U_;
#pragma unroll
  for (int r = 0; r < 4; ++r) {
    OUT[fb + (long)(b0 + row0 + r) * U_ + uu]                 = c[r];
    OUT[fb + (long)B_ * U_ + (long)(b0 + row0 + r) * U_ + uu] = hn[r];
  }
}

extern "C" void kernel_launch(void* const* d_in, const int* in_sizes, int n_in,
                              void* d_out, int out_size, void* d_ws, size_t ws_size,
                              hipStream_t stream) {
  const float* X  = (const float*)d_in[0];  // [T,B,F]
  const float* ST = (const float*)d_in[1];  // [2,B,U]
  const float* DN = (const float*)d_in[2];  // [T,B]
  const float* WX = (const float*)d_in[3];  // [F,4U]
  const float* WH = (const float*)d_in[4];  // [U,4U]
  float* OUT = (float*)d_out;               // [T*B*U + 2*B*U]

  if (ws_size >= ZX_BYTES) {
    float* ZX = (float*)d_ws;
    zx_gemm_kernel<<<dim3(256), dim3(512), 0, stream>>>(X, WX, ZX);
    lstm_zx_kernel<<<dim3(16), dim3(512), 0, stream>>>(ZX, ST, DN, WH, OUT);
  } else {
    lstm_fb_kernel<<<dim3(16), dim3(512), 0, stream>>>(X, ST, DN, WX, WH, OUT);
  }
}

// Round 6
// 796.833 us; speedup vs baseline: 1.9304x; 1.0219x over previous
//
#include <hip/hip_runtime.h>

#define T_  512
#define B_  256
#define F_  128
#define U_  128
#define G4_ 512
#define L2E 1.4426950408889634f
#define NBLK 32                              // recurrent blocks (8 real rows each)
#define ZSTRIDE (16 * 512 * 16)              // zx floats per timestep (R4 layout)
#define ZX_BYTES ((size_t)T_ * B_ * G4_ * 4) // 268435456

using f32x4 = __attribute__((ext_vector_type(4))) float;
using s16x8 = __attribute__((ext_vector_type(8))) short;
using u32x4 = __attribute__((ext_vector_type(4))) unsigned int;

__device__ __forceinline__ unsigned fbits(float f) { return __builtin_bit_cast(unsigned, f); }

// scalar RNE fp32->bf16 (weight preamble only)
__device__ __forceinline__ unsigned short f2bf(float f) {
  unsigned u = fbits(f);
  u += 0x7FFFu + ((u >> 16) & 1u);
  return (unsigned short)(u >> 16);
}
// hardware RNE pack: low16 = bf16(lo), high16 = bf16(hi)
__device__ __forceinline__ unsigned cvt_pk_bf16(float lo, float hi) {
  unsigned r;
  asm("v_cvt_pk_bf16_f32 %0, %1, %2" : "=v"(r) : "v"(lo), "v"(hi));
  return r;
}
__device__ __forceinline__ s16x8 pack8(f32x4 a, f32x4 b) {
  u32x4 w;
  w[0] = cvt_pk_bf16(a[0], a[1]);
  w[1] = cvt_pk_bf16(a[2], a[3]);
  w[2] = cvt_pk_bf16(b[0], b[1]);
  w[3] = cvt_pk_bf16(b[2], b[3]);
  return __builtin_bit_cast(s16x8, w);
}
// barrier waiting only on LDS ops — global loads/stores stay in flight
__device__ __forceinline__ void sync_lds() {
  asm volatile("s_waitcnt lgkmcnt(0)\n\ts_barrier" ::: "memory");
}

// ============ kernel 1 (VERBATIM R4, known-good): zx = X @ (Wx*scale), f32 ============
// Output layout: ZX[((G*8 + wave)*64 + lane)*16 + g*4 + r], G = global 16-row tile.
__global__ __launch_bounds__(512, 1)
void zx_gemm_kernel(const float* __restrict__ X, const float* __restrict__ WX,
                    float* __restrict__ ZX)
{
  const int tid  = threadIdx.x;
  const int w    = tid >> 6;
  const int lane = tid & 63;
  const int lr   = lane & 15;
  const int lk   = lane >> 4;

  s16x8 bWx[4][4];
#pragma unroll
  for (int g = 0; g < 4; ++g) {
    const float scl = (g == 3) ? 2.0f * L2E : L2E;   // u-gate carries tanh's 2x
    const int col = g * 128 + w * 16 + lr;
#pragma unroll
    for (int kc = 0; kc < 4; ++kc) {
      s16x8 wx;
#pragma unroll
      for (int e = 0; e < 8; ++e) {
        const int k = kc * 32 + lk * 8 + e;
        wx[e] = (short)f2bf(WX[k * G4_ + col] * scl);
      }
      bWx[g][kc] = wx;
    }
  }

  const int G0 = blockIdx.x * 32;
  const float* xp = X + (size_t)(G0 * 16 + lr) * F_ + lk * 8;
  float*       zp = ZX + ((size_t)(G0 * 8 + w) * 64 + lane) * 16;

  for (int grp = 0; grp < 32; ++grp) {
    s16x8 xa[4];
#pragma unroll
    for (int kc = 0; kc < 4; ++kc)
      xa[kc] = pack8(*(const f32x4*)(xp + kc * 32), *(const f32x4*)(xp + kc * 32 + 4));
#pragma unroll
    for (int g = 0; g < 4; ++g) {
      f32x4 a = {0.f, 0.f, 0.f, 0.f};
#pragma unroll
      for (int kc = 0; kc < 4; ++kc)
        a = __builtin_amdgcn_mfma_f32_16x16x32_bf16(xa[kc], bWx[g][kc], a, 0, 0, 0);
      *(f32x4*)(zp + g * 4) = a;
    }
    xp += 16 * F_;
    zp += 8 * 64 * 16;
  }
}

// ====== kernel 2: recurrent scan, 32 blocks x 8 real rows; remap ONLY in reader addr ======
__global__ __launch_bounds__(512, 1)
void lstm_zx32_kernel(const float* __restrict__ ZX, const float* __restrict__ ST,
                      const float* __restrict__ DN, const float* __restrict__ WH,
                      float* __restrict__ OUT)
{
  __shared__ __align__(16) short hbuf[2][16 * U_];

  const int tid  = threadIdx.x;
  const int w    = tid >> 6;
  const int lane = tid & 63;
  const int lr   = lane & 15;
  const int lk   = lane >> 4;
  const int lkm  = lk & 1;            // mirrored row-group (pads duplicate reals)
  const bool rl  = (lk < 2);          // lanes owning real output rows
  const int b0   = blockIdx.x * 8;
  const int row0 = lk * 4;            // C/D row incl. pad (0..15)
  const int row0r = lkm * 4;          // real (mirrored) row group (0 or 4)
  const int uu   = w * 16 + lr;

  const int doff = b0 + row0r;
  const int ooff = (b0 + row0r) * U_ + uu;

  // Wh, pre-scaled per gate (log2e; 2*log2e for u); k-coverage uses lk (all lanes real k)
  s16x8 bWh[4][4];
#pragma unroll
  for (int g = 0; g < 4; ++g) {
    const float scl = (g == 3) ? 2.0f * L2E : L2E;
    const int col = g * 128 + uu;
#pragma unroll
    for (int kc = 0; kc < 4; ++kc) {
      s16x8 wh;
#pragma unroll
      for (int e = 0; e < 8; ++e) {
        const int k = kc * 32 + lk * 8 + e;
        wh[e] = (short)f2bf(WH[k * G4_ + col] * scl);
      }
      bWh[g][kc] = wh;
    }
  }

  // fp32 state (pads mirror real rows; finite duplicates, never stored)
  float c[4], hn[4];
#pragma unroll
  for (int r = 0; r < 4; ++r) {
    c[r]  = ST[(b0 + row0r + r) * U_ + uu];
    hn[r] = ST[(B_ + b0 + row0r + r) * U_ + uu];
  }
  { // mask m(0), publish masked h(0) (rows 0-7 real, 8-15 mirrors for the A-fragment)
    f32x4 d = *(const f32x4*)&DN[doff];
#pragma unroll
    for (int r = 0; r < 4; ++r) {
      const float m = 1.0f - d[r];
      c[r] *= m;
      const float hm = hn[r] * m;
      const int row = row0 + r;
      const int sl  = (uu >> 3) ^ row;
      hbuf[0][row * U_ + sl * 8 + (uu & 7)] = (short)cvt_pk_bf16(hm, 0.f);
    }
  }

  // zx base: reader remap into R4's identity layout.
  // Need writer thread (tile bt = bx>>1 within t, wave w, lane lkw*16+lr),
  // lkw = (bx&1)*2 + lkm. Pads (lk>=2) duplicate the real lanes' address.
  const int bt  = blockIdx.x >> 1;
  const int lkw = (blockIdx.x & 1) * 2 + lkm;
  const float* zbase = ZX + ((size_t)(bt * 8 + w) * 64 + lkw * 16 + lr) * 16;

  f32x4 zxA[4], zxB[4], dv;
#pragma unroll
  for (int g = 0; g < 4; ++g) zxA[g] = *(const f32x4*)(zbase + g * 4);
#pragma unroll
  for (int g = 0; g < 4; ++g) zxB[g] = *(const f32x4*)(zbase + ZSTRIDE + g * 4);
  dv = *(const f32x4*)&DN[B_ + doff];
  sync_lds();  // h(0) visible

  const float* Zt  = zbase + 2 * (size_t)ZSTRIDE;  // zx(t+2)
  const float* DNt = DN + 2 * B_;
  float*       Ot  = OUT;

  auto step = [&](const int p, const bool pub, const bool pre, f32x4 (&zxC)[4]) {
    // a) h(t) fragments from swizzled LDS
    s16x8 ah[4];
#pragma unroll
    for (int kc = 0; kc < 4; ++kc) {
      const int sl = (kc * 4 + lk) ^ lr;
      ah[kc] = *(const s16x8*)&hbuf[p][lr * U_ + sl * 8];
    }
    // b) z = zx + h @ Wh (prefetched zx regs ARE the C-init)
    f32x4 az[4];
#pragma unroll
    for (int g = 0; g < 4; ++g) {
      f32x4 a = zxC[g];
#pragma unroll
      for (int kc = 0; kc < 4; ++kc)
        a = __builtin_amdgcn_mfma_f32_16x16x32_bf16(ah[kc], bWh[g][kc], a, 0, 0, 0);
      az[g] = a;
    }
    // c) refill zx(t+2)
    if (pre) {
#pragma unroll
      for (int g = 0; g < 4; ++g) zxC[g] = *(const f32x4*)(Zt + g * 4);
    }
    // d) activations (z pre-scaled by log2e -> bare v_exp2), update, store
#pragma unroll
    for (int r = 0; r < 4; ++r) {
      const float eA = exp2f(-az[0][r]);
      const float eC = exp2f(-az[1][r]);
      const float eD = exp2f(-az[2][r]);
      const float eB = exp2f(-az[3][r]);
      const float iu = (1.0f - eB) * __builtin_amdgcn_rcpf((1.0f + eA) * (1.0f + eB));
      const float fg = __builtin_amdgcn_rcpf(1.0f + eC);
      const float cn = fmaf(fg, c[r], iu);
      const float ce = fminf(fmaxf(cn, -15.0f), 15.0f);
      const float eE = exp2f(-2.0f * L2E * ce);
      const float h  = (1.0f - eE) * __builtin_amdgcn_rcpf((1.0f + eD) * (1.0f + eE));
      c[r]  = cn;
      hn[r] = h;
      if (rl) Ot[ooff + r * U_] = h;
    }
    // e) dones for t+1 (held), issue d(t+2)
    f32x4 dcur = dv;
    if (pre) dv = *(const f32x4*)(DNt + doff);
    // f) mask m(t+1), publish masked h(t+1)
    if (pub) {
#pragma unroll
      for (int r = 0; r < 4; ++r) {
        const float m = 1.0f - dcur[r];
        c[r] *= m;
        const float hm = hn[r] * m;
        const int row = row0 + r;
        const int sl  = (uu >> 3) ^ row;
        hbuf[p ^ 1][row * U_ + sl * 8 + (uu & 7)] = (short)cvt_pk_bf16(hm, 0.f);
      }
    }
    sync_lds();
  };

  for (int t = 0; t < T_; t += 2) {
    step(0, true, t + 2 < T_, zxA);
    Zt += ZSTRIDE; DNt += B_; Ot += B_ * U_;
    step(1, t + 2 < T_, t + 3 < T_, zxB);
    Zt += ZSTRIDE; DNt += B_; Ot += B_ * U_;
  }

  // final carry (c, h) after step T-1, unmasked — real rows only
  if (rl) {
    const long fb = (long)T_ * B_ * U_;
#pragma unroll
    for (int r = 0; r < 4; ++r) {
      OUT[fb + (long)(b0 + row0r + r) * U_ + uu]                 = c[r];
      OUT[fb + (long)B_ * U_ + (long)(b0 + row0r + r) * U_ + uu] = hn[r];
    }
  }
}

// ============ fallback (R3 kernel verbatim): used when ws is too small ============
__global__ __launch_bounds__(512, 1)
void lstm_fb_kernel(const float* __restrict__ X, const float* __restrict__ ST,
                    const float* __restrict__ DN, const float* __restrict__ WX,
                    const float* __restrict__ WH, float* __restrict__ OUT)
{
  __shared__ __align__(16) short hbuf[2][16 * U_];

  const int tid  = threadIdx.x;
  const int w    = tid >> 6;
  const int lane = tid & 63;
  const int lr   = lane & 15;
  const int lk   = lane >> 4;
  const int b0   = blockIdx.x * 16;
  const int row0 = lk * 4;
  const int uu   = w * 16 + lr;

  const int xoff = (b0 + lr) * F_ + lk * 8;
  const int doff = b0 + row0;
  const int ooff = (b0 + row0) * U_ + uu;

  s16x8 bWh[4][4], bWx[4][4];
#pragma unroll
  for (int g = 0; g < 4; ++g) {
    const int col = g * 128 + uu;
#pragma unroll
    for (int kc = 0; kc < 4; ++kc) {
      s16x8 wh, wx;
#pragma unroll
      for (int e = 0; e < 8; ++e) {
        const int k = kc * 32 + lk * 8 + e;
        wh[e] = (short)f2bf(WH[k * G4_ + col]);
        wx[e] = (short)f2bf(WX[k * G4_ + col]);
      }
      bWh[g][kc] = wh;
      bWx[g][kc] = wx;
    }
  }

  float c[4], hn[4];
#pragma unroll
  for (int r = 0; r < 4; ++r) {
    c[r]  = ST[(b0 + row0 + r) * U_ + uu];
    hn[r] = ST[(B_ + b0 + row0 + r) * U_ + uu];
  }
  {
    f32x4 d = *(const f32x4*)&DN[doff];
#pragma unroll
    for (int r = 0; r < 4; ++r) {
      const float m = 1.0f - d[r];
      c[r] *= m;
      const int row = row0 + r;
      const int sl  = (uu >> 3) ^ row;
      hbuf[0][row * U_ + sl * 8 + (uu & 7)] = (short)cvt_pk_bf16(hn[r] * m, 0.f);
    }
  }

  f32x4 xv0[4], xv1[4], dv;
  f32x4 accA[4], accB[4];
  {
    const float* xp = X + xoff;
    s16x8 xa[4];
#pragma unroll
    for (int kc = 0; kc < 4; ++kc)
      xa[kc] = pack8(*(const f32x4*)(xp + kc * 32), *(const f32x4*)(xp + kc * 32 + 4));
#pragma unroll
    for (int g = 0; g < 4; ++g) {
      f32x4 a = {0.f, 0.f, 0.f, 0.f};
#pragma unroll
      for (int kc = 0; kc < 4; ++kc)
        a = __builtin_amdgcn_mfma_f32_16x16x32_bf16(xa[kc], bWx[g][kc], a, 0, 0, 0);
      accA[g] = a;
    }
#pragma unroll
    for (int kc = 0; kc < 4; ++kc) {
      xv0[kc] = *(const f32x4*)(X + B_ * F_ + xoff + kc * 32);
      xv1[kc] = *(const f32x4*)(X + B_ * F_ + xoff + kc * 32 + 4);
    }
    dv = *(const f32x4*)(DN + B_ + doff);
  }
  sync_lds();

  const float* Xt  = X + 2 * B_ * F_;
  const float* DNt = DN + 2 * B_;
  float*       Ot  = OUT;

  auto step = [&](const int p, const bool act_x, const bool pre_x,
                  f32x4 (&accZ)[4], f32x4 (&accX)[4]) {
    s16x8 ah[4];
#pragma unroll
    for (int kc = 0; kc < 4; ++kc) {
      const int sl = (kc * 4 + lk) ^ lr;
      ah[kc] = *(const s16x8*)&hbuf[p][lr * U_ + sl * 8];
    }
#pragma unroll
    for (int g = 0; g < 4; ++g) {
      f32x4 a = accZ[g];
#pragma unroll
      for (int kc = 0; kc < 4; ++kc)
        a = __builtin_amdgcn_mfma_f32_16x16x32_bf16(ah[kc], bWh[g][kc], a, 0, 0, 0);
      accZ[g] = a;
    }
#pragma unroll
    for (int r = 0; r < 4; ++r) {
      const float eA = __expf(-accZ[0][r]);
      const float eB = __expf(-2.0f * accZ[3][r]);
      const float eC = __expf(-accZ[1][r]);
      const float eD = __expf(-accZ[2][r]);
      const float iu = (1.0f - eB) * __builtin_amdgcn_rcpf((1.0f + eA) * (1.0f + eB));
      const float fg = __builtin_amdgcn_rcpf(1.0f + eC);
      const float cn = fmaf(fg, c[r], iu);
      const float ce = fminf(fmaxf(cn, -30.0f), 30.0f);
      const float eE = __expf(-2.0f * ce);
      const float h  = (1.0f - eE) * __builtin_amdgcn_rcpf((1.0f + eD) * (1.0f + eE));
      c[r]  = cn;
      hn[r] = h;
      Ot[ooff + r * U_] = h;
    }
    if (act_x) {
      s16x8 xa[4];
#pragma unroll
      for (int kc = 0; kc < 4; ++kc) xa[kc] = pack8(xv0[kc], xv1[kc]);
#pragma unroll
      for (int g = 0; g < 4; ++g) {
        f32x4 a = {0.f, 0.f, 0.f, 0.f};
#pragma unroll
        for (int kc = 0; kc < 4; ++kc)
          a = __builtin_amdgcn_mfma_f32_16x16x32_bf16(xa[kc], bWx[g][kc], a, 0, 0, 0);
        accX[g] = a;
      }
    }
    f32x4 dcur = dv;
    if (pre_x) {
#pragma unroll
      for (int kc = 0; kc < 4; ++kc) {
        xv0[kc] = *(const f32x4*)(Xt + xoff + kc * 32);
        xv1[kc] = *(const f32x4*)(Xt + xoff + kc * 32 + 4);
      }
      dv = *(const f32x4*)(DNt + doff);
    }
    if (act_x) {
#pragma unroll
      for (int r = 0; r < 4; ++r) {
        const float m = 1.0f - dcur[r];
        c[r] *= m;
        const int row = row0 + r;
        const int sl  = (uu >> 3) ^ row;
        hbuf[p ^ 1][row * U_ + sl * 8 + (uu & 7)] = (short)cvt_pk_bf16(hn[r] * m, 0.f);
      }
    }
    sync_lds();
  };

  for (int t = 0; t < T_; t += 2) {
    step(0, true, t + 2 < T_, accA, accB);
    Xt += B_ * F_; DNt += B_; Ot += B_ * U_;
    step(1, t + 2 < T_, t + 3 < T_, accB, accA);
    Xt += B_ * F_; DNt += B_; Ot += B_ * U_;
  }

  const long fb = (long)T_ * B_ * U_;
#pragma unroll
  for (int r = 0; r < 4; ++r) {
    OUT[fb + (long)(b0 + row0 + r) * U_ + uu]                 = c[r];
    OUT[fb + (long)B_ * U_ + (long)(b0 + row0 + r) * U_ + uu] = hn[r];
  }
}

extern "C" void kernel_launch(void* const* d_in, const int* in_sizes, int n_in,
                              void* d_out, int out_size, void* d_ws, size_t ws_size,
                              hipStream_t stream) {
  const float* X  = (const float*)d_in[0];  // [T,B,F]
  const float* ST = (const float*)d_in[1];  // [2,B,U]
  const float* DN = (const float*)d_in[2];  // [T,B]
  const float* WX = (const float*)d_in[3];  // [F,4U]
  const float* WH = (const float*)d_in[4];  // [U,4U]
  float* OUT = (float*)d_out;               // [T*B*U + 2*B*U]

  if (ws_size >= ZX_BYTES) {
    float* ZX = (float*)d_ws;
    zx_gemm_kernel<<<dim3(256), dim3(512), 0, stream>>>(X, WX, ZX);
    lstm_zx32_kernel<<<dim3(NBLK), dim3(512), 0, stream>>>(ZX, ST, DN, WH, OUT);
  } else {
    lstm_fb_kernel<<<dim3(16), dim3(512), 0, stream>>>(X, ST, DN, WX, WH, OUT);
  }
}

// Round 7
// 672.913 us; speedup vs baseline: 2.2859x; 1.1842x over previous
//
#include <hip/hip_runtime.h>

#define T_  512
#define B_  256
#define F_  128
#define U_  128
#define G4_ 512
#define L2E 1.4426950408889634f
#define NBLK 32                              // recurrent blocks (8 real rows each)
#define ZSTRIDE (16 * 512 * 16)              // zx floats per timestep (R4 layout)
#define ZX_BYTES ((size_t)T_ * B_ * G4_ * 4) // 268435456

using f32x4 = __attribute__((ext_vector_type(4))) float;
using f32x2 = __attribute__((ext_vector_type(2))) float;
using s16x8 = __attribute__((ext_vector_type(8))) short;
using u32x4 = __attribute__((ext_vector_type(4))) unsigned int;

__device__ __forceinline__ unsigned fbits(float f) { return __builtin_bit_cast(unsigned, f); }

// scalar RNE fp32->bf16 (weight preamble only)
__device__ __forceinline__ unsigned short f2bf(float f) {
  unsigned u = fbits(f);
  u += 0x7FFFu + ((u >> 16) & 1u);
  return (unsigned short)(u >> 16);
}
// hardware RNE pack: low16 = bf16(lo), high16 = bf16(hi)
__device__ __forceinline__ unsigned cvt_pk_bf16(float lo, float hi) {
  unsigned r;
  asm("v_cvt_pk_bf16_f32 %0, %1, %2" : "=v"(r) : "v"(lo), "v"(hi));
  return r;
}
__device__ __forceinline__ s16x8 pack8(f32x4 a, f32x4 b) {
  u32x4 w;
  w[0] = cvt_pk_bf16(a[0], a[1]);
  w[1] = cvt_pk_bf16(a[2], a[3]);
  w[2] = cvt_pk_bf16(b[0], b[1]);
  w[3] = cvt_pk_bf16(b[2], b[3]);
  return __builtin_bit_cast(s16x8, w);
}
// barrier waiting only on LDS ops — global loads/stores stay in flight
__device__ __forceinline__ void sync_lds() {
  asm volatile("s_waitcnt lgkmcnt(0)\n\ts_barrier" ::: "memory");
}

// ============ kernel 1 (VERBATIM R4, known-good): zx = X @ (Wx*scale), f32 ============
// Output layout: ZX[((G*8 + wave)*64 + lane)*16 + g*4 + r], G = global 16-row tile.
__global__ __launch_bounds__(512, 1)
void zx_gemm_kernel(const float* __restrict__ X, const float* __restrict__ WX,
                    float* __restrict__ ZX)
{
  const int tid  = threadIdx.x;
  const int w    = tid >> 6;
  const int lane = tid & 63;
  const int lr   = lane & 15;
  const int lk   = lane >> 4;

  s16x8 bWx[4][4];
#pragma unroll
  for (int g = 0; g < 4; ++g) {
    const float scl = (g == 3) ? 2.0f * L2E : L2E;   // u-gate carries tanh's 2x
    const int col = g * 128 + w * 16 + lr;
#pragma unroll
    for (int kc = 0; kc < 4; ++kc) {
      s16x8 wx;
#pragma unroll
      for (int e = 0; e < 8; ++e) {
        const int k = kc * 32 + lk * 8 + e;
        wx[e] = (short)f2bf(WX[k * G4_ + col] * scl);
      }
      bWx[g][kc] = wx;
    }
  }

  const int G0 = blockIdx.x * 32;
  const float* xp = X + (size_t)(G0 * 16 + lr) * F_ + lk * 8;
  float*       zp = ZX + ((size_t)(G0 * 8 + w) * 64 + lane) * 16;

  for (int grp = 0; grp < 32; ++grp) {
    s16x8 xa[4];
#pragma unroll
    for (int kc = 0; kc < 4; ++kc)
      xa[kc] = pack8(*(const f32x4*)(xp + kc * 32), *(const f32x4*)(xp + kc * 32 + 4));
#pragma unroll
    for (int g = 0; g < 4; ++g) {
      f32x4 a = {0.f, 0.f, 0.f, 0.f};
#pragma unroll
      for (int kc = 0; kc < 4; ++kc)
        a = __builtin_amdgcn_mfma_f32_16x16x32_bf16(xa[kc], bWx[g][kc], a, 0, 0, 0);
      *(f32x4*)(zp + g * 4) = a;
    }
    xp += 16 * F_;
    zp += 8 * 64 * 16;
  }
}

// ====== kernel 2: recurrent scan, 32 blocks x 8 rows; mirror-SPLIT activations ======
// Mirror pairs (lane, lane^32) hold bit-identical az[g][0..3]. Lanes<32 activate
// rows {0,1}, lanes>=32 rows {2,3}; partner rows arrive via one packed shfl_xor.
__global__ __launch_bounds__(512, 1)
void lstm_zx32s_kernel(const float* __restrict__ ZX, const float* __restrict__ ST,
                       const float* __restrict__ DN, const float* __restrict__ WH,
                       float* __restrict__ OUT)
{
  __shared__ __align__(16) short hbuf[2][16 * U_];

  const int tid  = threadIdx.x;
  const int w    = tid >> 6;
  const int lane = tid & 63;
  const int lr   = lane & 15;
  const int lk   = lane >> 4;
  const int lkm  = lk & 1;            // mirrored row-group select
  const int r0   = (lk >> 1) * 2;     // activation rows owned: r0, r0+1
  const int b0   = blockIdx.x * 8;
  const int row0 = lk * 4;            // C/D row base incl. pads (0..15)
  const int row0r = lkm * 4;          // real row group (0 or 4)
  const int uu   = w * 16 + lr;

  const int doff2 = b0 + row0r + r0;                 // this lane's 2 dones
  const int ooff2 = (b0 + row0r + r0) * U_ + uu;     // this lane's 2 OUT rows

  // Wh, pre-scaled per gate (log2e; 2*log2e for u)
  s16x8 bWh[4][4];
#pragma unroll
  for (int g = 0; g < 4; ++g) {
    const float scl = (g == 3) ? 2.0f * L2E : L2E;
    const int col = g * 128 + uu;
#pragma unroll
    for (int kc = 0; kc < 4; ++kc) {
      s16x8 wh;
#pragma unroll
      for (int e = 0; e < 8; ++e) {
        const int k = kc * 32 + lk * 8 + e;
        wh[e] = (short)f2bf(WH[k * G4_ + col] * scl);
      }
      bWh[g][kc] = wh;
    }
  }

  // fp32 state: 2 rows per lane
  float c[2], hn[2];
#pragma unroll
  for (int j = 0; j < 2; ++j) {
    c[j]  = ST[(b0 + row0r + r0 + j) * U_ + uu];
    hn[j] = ST[(B_ + b0 + row0r + r0 + j) * U_ + uu];
  }
  { // mask m(0), exchange with partner, publish all 4 C/D rows
    f32x2 d2 = *(const f32x2*)&DN[doff2];
    const float m0 = 1.0f - d2[0], m1 = 1.0f - d2[1];
    c[0] *= m0; c[1] *= m1;
    const unsigned pkd = cvt_pk_bf16(hn[0] * m0, hn[1] * m1);
    const unsigned prt = __shfl_xor(pkd, 32);
    const unsigned plo = (r0 == 0) ? pkd : prt;   // rows row0+0,1
    const unsigned phi = (r0 == 0) ? prt : pkd;   // rows row0+2,3
    const int base = row0 * U_;
    hbuf[0][base + 0 * U_ + ((((uu >> 3) ^ (row0 + 0)) & 15) * 8) + (uu & 7)] = (short)plo;
    hbuf[0][base + 1 * U_ + ((((uu >> 3) ^ (row0 + 1)) & 15) * 8) + (uu & 7)] = (short)(plo >> 16);
    hbuf[0][base + 2 * U_ + ((((uu >> 3) ^ (row0 + 2)) & 15) * 8) + (uu & 7)] = (short)phi;
    hbuf[0][base + 3 * U_ + ((((uu >> 3) ^ (row0 + 3)) & 15) * 8) + (uu & 7)] = (short)(phi >> 16);
  }

  // zx base: reader remap into R4 identity layout (pads duplicate real addresses)
  const int bt  = blockIdx.x >> 1;
  const int lkw = (blockIdx.x & 1) * 2 + lkm;
  const float* zbase = ZX + ((size_t)(bt * 8 + w) * 64 + lkw * 16 + lr) * 16;

  f32x4 zxA[4], zxB[4];
  f32x2 dv;
#pragma unroll
  for (int g = 0; g < 4; ++g) zxA[g] = *(const f32x4*)(zbase + g * 4);
#pragma unroll
  for (int g = 0; g < 4; ++g) zxB[g] = *(const f32x4*)(zbase + ZSTRIDE + g * 4);
  dv = *(const f32x2*)&DN[B_ + doff2];
  sync_lds();  // h(0) visible

  const float* Zt  = zbase + 2 * (size_t)ZSTRIDE;  // zx(t+2)
  const float* DNt = DN + 2 * B_;
  float*       Ot  = OUT;

  auto step = [&](const int p, const bool pub, const bool pre, f32x4 (&zxC)[4]) {
    // a) h(t) fragments from swizzled LDS
    s16x8 ah[4];
#pragma unroll
    for (int kc = 0; kc < 4; ++kc) {
      const int sl = (kc * 4 + lk) ^ lr;
      ah[kc] = *(const s16x8*)&hbuf[p][lr * U_ + sl * 8];
    }
    // b) z = zx + h @ Wh (prefetched zx regs ARE the C-init)
    f32x4 az[4];
#pragma unroll
    for (int g = 0; g < 4; ++g) {
      f32x4 a = zxC[g];
#pragma unroll
      for (int kc = 0; kc < 4; ++kc)
        a = __builtin_amdgcn_mfma_f32_16x16x32_bf16(ah[kc], bWh[g][kc], a, 0, 0, 0);
      az[g] = a;
    }
    // c) refill zx(t+2)
    if (pre) {
#pragma unroll
      for (int g = 0; g < 4; ++g) zxC[g] = *(const f32x4*)(Zt + g * 4);
    }
    // d) activations for THIS lane's 2 rows only (partner does the other 2)
#pragma unroll
    for (int j = 0; j < 2; ++j) {
      const int r = r0 + j;
      const float eA = exp2f(-az[0][r]);
      const float eC = exp2f(-az[1][r]);
      const float eD = exp2f(-az[2][r]);
      const float eB = exp2f(-az[3][r]);
      const float iu = (1.0f - eB) * __builtin_amdgcn_rcpf((1.0f + eA) * (1.0f + eB));
      const float fg = __builtin_amdgcn_rcpf(1.0f + eC);
      const float cn = fmaf(fg, c[j], iu);
      const float ce = fminf(fmaxf(cn, -15.0f), 15.0f);
      const float eE = exp2f(-2.0f * L2E * ce);
      const float h  = (1.0f - eE) * __builtin_amdgcn_rcpf((1.0f + eD) * (1.0f + eE));
      c[j]  = cn;
      hn[j] = h;
      Ot[ooff2 + j * U_] = h;
    }
    // e) dones for t+1 (held), issue d(t+2)
    f32x2 dcur = dv;
    if (pre) dv = *(const f32x2*)(DNt + doff2);
    // f) mask m(t+1), exchange, publish all 4 C/D rows
    if (pub) {
      const float m0 = 1.0f - dcur[0], m1 = 1.0f - dcur[1];
      c[0] *= m0; c[1] *= m1;
      const unsigned pkd = cvt_pk_bf16(hn[0] * m0, hn[1] * m1);
      const unsigned prt = __shfl_xor(pkd, 32);
      const unsigned plo = (r0 == 0) ? pkd : prt;
      const unsigned phi = (r0 == 0) ? prt : pkd;
      short* hb = hbuf[p ^ 1] + row0 * U_ + (uu & 7);
      hb[0 * U_ + (((uu >> 3) ^ (row0 + 0)) & 15) * 8] = (short)plo;
      hb[1 * U_ + (((uu >> 3) ^ (row0 + 1)) & 15) * 8] = (short)(plo >> 16);
      hb[2 * U_ + (((uu >> 3) ^ (row0 + 2)) & 15) * 8] = (short)phi;
      hb[3 * U_ + (((uu >> 3) ^ (row0 + 3)) & 15) * 8] = (short)(phi >> 16);
    }
    sync_lds();
  };

  for (int t = 0; t < T_; t += 2) {
    step(0, true, t + 2 < T_, zxA);
    Zt += ZSTRIDE; DNt += B_; Ot += B_ * U_;
    step(1, t + 2 < T_, t + 3 < T_, zxB);
    Zt += ZSTRIDE; DNt += B_; Ot += B_ * U_;
  }

  // final carry (c, h) after step T-1, unmasked — 2 rows per lane, all lanes
  const long fb = (long)T_ * B_ * U_;
#pragma unroll
  for (int j = 0; j < 2; ++j) {
    OUT[fb + (long)(b0 + row0r + r0 + j) * U_ + uu]                 = c[j];
    OUT[fb + (long)B_ * U_ + (long)(b0 + row0r + r0 + j) * U_ + uu] = hn[j];
  }
}

// ============ fallback (R3 kernel verbatim): used when ws is too small ============
__global__ __launch_bounds__(512, 1)
void lstm_fb_kernel(const float* __restrict__ X, const float* __restrict__ ST,
                    const float* __restrict__ DN, const float* __restrict__ WX,
                    const float* __restrict__ WH, float* __restrict__ OUT)
{
  __shared__ __align__(16) short hbuf[2][16 * U_];

  const int tid  = threadIdx.x;
  const int w    = tid >> 6;
  const int lane = tid & 63;
  const int lr   = lane & 15;
  const int lk   = lane >> 4;
  const int b0   = blockIdx.x * 16;
  const int row0 = lk * 4;
  const int uu   = w * 16 + lr;

  const int xoff = (b0 + lr) * F_ + lk * 8;
  const int doff = b0 + row0;
  const int ooff = (b0 + row0) * U_ + uu;

  s16x8 bWh[4][4], bWx[4][4];
#pragma unroll
  for (int g = 0; g < 4; ++g) {
    const int col = g * 128 + uu;
#pragma unroll
    for (int kc = 0; kc < 4; ++kc) {
      s16x8 wh, wx;
#pragma unroll
      for (int e = 0; e < 8; ++e) {
        const int k = kc * 32 + lk * 8 + e;
        wh[e] = (short)f2bf(WH[k * G4_ + col]);
        wx[e] = (short)f2bf(WX[k * G4_ + col]);
      }
      bWh[g][kc] = wh;
      bWx[g][kc] = wx;
    }
  }

  float c[4], hn[4];
#pragma unroll
  for (int r = 0; r < 4; ++r) {
    c[r]  = ST[(b0 + row0 + r) * U_ + uu];
    hn[r] = ST[(B_ + b0 + row0 + r) * U_ + uu];
  }
  {
    f32x4 d = *(const f32x4*)&DN[doff];
#pragma unroll
    for (int r = 0; r < 4; ++r) {
      const float m = 1.0f - d[r];
      c[r] *= m;
      const int row = row0 + r;
      const int sl  = (uu >> 3) ^ row;
      hbuf[0][row * U_ + sl * 8 + (uu & 7)] = (short)cvt_pk_bf16(hn[r] * m, 0.f);
    }
  }

  f32x4 xv0[4], xv1[4], dv;
  f32x4 accA[4], accB[4];
  {
    const float* xp = X + xoff;
    s16x8 xa[4];
#pragma unroll
    for (int kc = 0; kc < 4; ++kc)
      xa[kc] = pack8(*(const f32x4*)(xp + kc * 32), *(const f32x4*)(xp + kc * 32 + 4));
#pragma unroll
    for (int g = 0; g < 4; ++g) {
      f32x4 a = {0.f, 0.f, 0.f, 0.f};
#pragma unroll
      for (int kc = 0; kc < 4; ++kc)
        a = __builtin_amdgcn_mfma_f32_16x16x32_bf16(xa[kc], bWx[g][kc], a, 0, 0, 0);
      accA[g] = a;
    }
#pragma unroll
    for (int kc = 0; kc < 4; ++kc) {
      xv0[kc] = *(const f32x4*)(X + B_ * F_ + xoff + kc * 32);
      xv1[kc] = *(const f32x4*)(X + B_ * F_ + xoff + kc * 32 + 4);
    }
    dv = *(const f32x4*)(DN + B_ + doff);
  }
  sync_lds();

  const float* Xt  = X + 2 * B_ * F_;
  const float* DNt = DN + 2 * B_;
  float*       Ot  = OUT;

  auto step = [&](const int p, const bool act_x, const bool pre_x,
                  f32x4 (&accZ)[4], f32x4 (&accX)[4]) {
    s16x8 ah[4];
#pragma unroll
    for (int kc = 0; kc < 4; ++kc) {
      const int sl = (kc * 4 + lk) ^ lr;
      ah[kc] = *(const s16x8*)&hbuf[p][lr * U_ + sl * 8];
    }
#pragma unroll
    for (int g = 0; g < 4; ++g) {
      f32x4 a = accZ[g];
#pragma unroll
      for (int kc = 0; kc < 4; ++kc)
        a = __builtin_amdgcn_mfma_f32_16x16x32_bf16(ah[kc], bWh[g][kc], a, 0, 0, 0);
      accZ[g] = a;
    }
#pragma unroll
    for (int r = 0; r < 4; ++r) {
      const float eA = __expf(-accZ[0][r]);
      const float eB = __expf(-2.0f * accZ[3][r]);
      const float eC = __expf(-accZ[1][r]);
      const float eD = __expf(-accZ[2][r]);
      const float iu = (1.0f - eB) * __builtin_amdgcn_rcpf((1.0f + eA) * (1.0f + eB));
      const float fg = __builtin_amdgcn_rcpf(1.0f + eC);
      const float cn = fmaf(fg, c[r], iu);
      const float ce = fminf(fmaxf(cn, -30.0f), 30.0f);
      const float eE = __expf(-2.0f * ce);
      const float h  = (1.0f - eE) * __builtin_amdgcn_rcpf((1.0f + eD) * (1.0f + eE));
      c[r]  = cn;
      hn[r] = h;
      Ot[ooff + r * U_] = h;
    }
    if (act_x) {
      s16x8 xa[4];
#pragma unroll
      for (int kc = 0; kc < 4; ++kc) xa[kc] = pack8(xv0[kc], xv1[kc]);
#pragma unroll
      for (int g = 0; g < 4; ++g) {
        f32x4 a = {0.f, 0.f, 0.f, 0.f};
#pragma unroll
        for (int kc = 0; kc < 4; ++kc)
          a = __builtin_amdgcn_mfma_f32_16x16x32_bf16(xa[kc], bWx[g][kc], a, 0, 0, 0);
        accX[g] = a;
      }
    }
    f32x4 dcur = dv;
    if (pre_x) {
#pragma unroll
      for (int kc = 0; kc < 4; ++kc) {
        xv0[kc] = *(const f32x4*)(Xt + xoff + kc * 32);
        xv1[kc] = *(const f32x4*)(Xt + xoff + kc * 32 + 4);
      }
      dv = *(const f32x4*)(DNt + doff);
    }
    if (act_x) {
#pragma unroll
      for (int r = 0; r < 4; ++r) {
        const float m = 1.0f - dcur[r];
        c[r] *= m;
        const int row = row0 + r;
        const int sl  = (uu >> 3) ^ row;
        hbuf[p ^ 1][row * U_ + sl * 8 + (uu & 7)] = (short)cvt_pk_bf16(hn[r] * m, 0.f);
      }
    }
    sync_lds();
  };

  for (int t = 0; t < T_; t += 2) {
    step(0, true, t + 2 < T_, accA, accB);
    Xt += B_ * F_; DNt += B_; Ot += B_ * U_;
    step(1, t + 2 < T_, t + 3 < T_, accB, accA);
    Xt += B_ * F_; DNt += B_; Ot += B_ * U_;
  }

  const long fb = (long)T_ * B_ * U_;
#pragma unroll
  for (int r = 0; r < 4; ++r) {
    OUT[fb + (long)(b0 + row0 + r) * U_ + uu]                 = c[r];
    OUT[fb + (long)B_ * U_ + (long)(b0 + row0 + r) * U_ + uu] = hn[r];
  }
}

extern "C" void kernel_launch(void* const* d_in, const int* in_sizes, int n_in,
                              void* d_out, int out_size, void* d_ws, size_t ws_size,
                              hipStream_t stream) {
  const float* X  = (const float*)d_in[0];  // [T,B,F]
  const float* ST = (const float*)d_in[1];  // [2,B,U]
  const float* DN = (const float*)d_in[2];  // [T,B]
  const float* WX = (const float*)d_in[3];  // [F,4U]
  const float* WH = (const float*)d_in[4];  // [U,4U]
  float* OUT = (float*)d_out;               // [T*B*U + 2*B*U]

  if (ws_size >= ZX_BYTES) {
    float* ZX = (float*)d_ws;
    zx_gemm_kernel<<<dim3(256), dim3(512), 0, stream>>>(X, WX, ZX);
    lstm_zx32s_kernel<<<dim3(NBLK), dim3(512), 0, stream>>>(ZX, ST, DN, WH, OUT);
  } else {
    lstm_fb_kernel<<<dim3(16), dim3(512), 0, stream>>>(X, ST, DN, WX, WH, OUT);
  }
}

// Round 8
// 617.860 us; speedup vs baseline: 2.4896x; 1.0891x over previous
//
#include <hip/hip_runtime.h>

#define T_  512
#define B_  256
#define F_  128
#define U_  128
#define G4_ 512
#define L2E 1.4426950408889634f
#define NBLK 32                              // recurrent blocks (8 real rows each)
#define ZSTRIDE (16 * 512 * 16)              // zx floats per timestep (R4 layout)
#define ZX_BYTES ((size_t)T_ * B_ * G4_ * 4) // 268435456

using f32x4 = __attribute__((ext_vector_type(4))) float;
using f32x2 = __attribute__((ext_vector_type(2))) float;
using s16x8 = __attribute__((ext_vector_type(8))) short;
using u32x4 = __attribute__((ext_vector_type(4))) unsigned int;

#if __has_builtin(__builtin_amdgcn_exp2f)
#define EXP2(x) __builtin_amdgcn_exp2f(x)    // bare v_exp_f32, no libcall
#else
#define EXP2(x) exp2f(x)
#endif

__device__ __forceinline__ unsigned fbits(float f) { return __builtin_bit_cast(unsigned, f); }

// scalar RNE fp32->bf16 (weight preamble only)
__device__ __forceinline__ unsigned short f2bf(float f) {
  unsigned u = fbits(f);
  u += 0x7FFFu + ((u >> 16) & 1u);
  return (unsigned short)(u >> 16);
}
// hardware RNE pack: low16 = bf16(lo), high16 = bf16(hi)
__device__ __forceinline__ unsigned cvt_pk_bf16(float lo, float hi) {
  unsigned r;
  asm("v_cvt_pk_bf16_f32 %0, %1, %2" : "=v"(r) : "v"(lo), "v"(hi));
  return r;
}
__device__ __forceinline__ s16x8 pack8(f32x4 a, f32x4 b) {
  u32x4 w;
  w[0] = cvt_pk_bf16(a[0], a[1]);
  w[1] = cvt_pk_bf16(a[2], a[3]);
  w[2] = cvt_pk_bf16(b[0], b[1]);
  w[3] = cvt_pk_bf16(b[2], b[3]);
  return __builtin_bit_cast(s16x8, w);
}
// barrier waiting only on LDS ops — global loads/stores stay in flight
__device__ __forceinline__ void sync_lds() {
  asm volatile("s_waitcnt lgkmcnt(0)\n\ts_barrier" ::: "memory");
}

// ============ kernel 1 (VERBATIM R4, known-good): zx = X @ (Wx*scale), f32 ============
// Output layout: ZX[((G*8 + wave)*64 + lane)*16 + g*4 + r], G = global 16-row tile.
__global__ __launch_bounds__(512, 1)
void zx_gemm_kernel(const float* __restrict__ X, const float* __restrict__ WX,
                    float* __restrict__ ZX)
{
  const int tid  = threadIdx.x;
  const int w    = tid >> 6;
  const int lane = tid & 63;
  const int lr   = lane & 15;
  const int lk   = lane >> 4;

  s16x8 bWx[4][4];
#pragma unroll
  for (int g = 0; g < 4; ++g) {
    const float scl = (g == 3) ? 2.0f * L2E : L2E;   // u-gate carries tanh's 2x
    const int col = g * 128 + w * 16 + lr;
#pragma unroll
    for (int kc = 0; kc < 4; ++kc) {
      s16x8 wx;
#pragma unroll
      for (int e = 0; e < 8; ++e) {
        const int k = kc * 32 + lk * 8 + e;
        wx[e] = (short)f2bf(WX[k * G4_ + col] * scl);
      }
      bWx[g][kc] = wx;
    }
  }

  const int G0 = blockIdx.x * 32;
  const float* xp = X + (size_t)(G0 * 16 + lr) * F_ + lk * 8;
  float*       zp = ZX + ((size_t)(G0 * 8 + w) * 64 + lane) * 16;

  for (int grp = 0; grp < 32; ++grp) {
    s16x8 xa[4];
#pragma unroll
    for (int kc = 0; kc < 4; ++kc)
      xa[kc] = pack8(*(const f32x4*)(xp + kc * 32), *(const f32x4*)(xp + kc * 32 + 4));
#pragma unroll
    for (int g = 0; g < 4; ++g) {
      f32x4 a = {0.f, 0.f, 0.f, 0.f};
#pragma unroll
      for (int kc = 0; kc < 4; ++kc)
        a = __builtin_amdgcn_mfma_f32_16x16x32_bf16(xa[kc], bWx[g][kc], a, 0, 0, 0);
      *(f32x4*)(zp + g * 4) = a;
    }
    xp += 16 * F_;
    zp += 8 * 64 * 16;
  }
}

// ====== kernel 2: recurrent scan — mirror-split activations, VALU-surgery version ======
// vs R7: (1) bare v_exp via builtin; (2) no shfl: owner lane writes its 2 rows to both
// real+mirror hbuf slots; (3) uniform-base + thread-const-offset addressing (saddr form).
__global__ __launch_bounds__(512, 1)
void lstm_zx32v_kernel(const float* __restrict__ ZX, const float* __restrict__ ST,
                       const float* __restrict__ DN, const float* __restrict__ WH,
                       float* __restrict__ OUT)
{
  __shared__ __align__(16) short hbuf[2][16 * U_];

  const int tid  = threadIdx.x;
  const int w    = tid >> 6;
  const int lane = tid & 63;
  const int lr   = lane & 15;
  const int lk   = lane >> 4;
  const int lkm  = lk & 1;            // mirrored row-group select
  const int r0   = (lk >> 1) * 2;     // owned az rows: r0, r0+1
  const int b0   = blockIdx.x * 8;
  const int wr0  = lkm * 4 + r0;      // owned real row (0..7): lk=0:{0,1} 2:{2,3} 1:{4,5} 3:{6,7}
  const int uu   = w * 16 + lr;

  const int doff2 = b0 + wr0;                    // this lane's 2 dones
  const int ooff2 = (b0 + wr0) * U_ + uu;        // this lane's 2 OUT rows

  // hbuf addresses (shorts), thread-constant: real rows wr0,wr0+1 and mirrors +8
  const int hA0 = (wr0 + 0) * U_ + ((((uu >> 3) ^ (wr0 + 0)) & 15) * 8) + (uu & 7);
  const int hA1 = (wr0 + 1) * U_ + ((((uu >> 3) ^ (wr0 + 1)) & 15) * 8) + (uu & 7);
  const int hB0 = (wr0 + 8) * U_ + ((((uu >> 3) ^ (wr0 + 8)) & 15) * 8) + (uu & 7);
  const int hB1 = (wr0 + 9) * U_ + ((((uu >> 3) ^ (wr0 + 9)) & 15) * 8) + (uu & 7);

  // Wh, pre-scaled per gate (log2e; 2*log2e for u)
  s16x8 bWh[4][4];
#pragma unroll
  for (int g = 0; g < 4; ++g) {
    const float scl = (g == 3) ? 2.0f * L2E : L2E;
    const int col = g * 128 + uu;
#pragma unroll
    for (int kc = 0; kc < 4; ++kc) {
      s16x8 wh;
#pragma unroll
      for (int e = 0; e < 8; ++e) {
        const int k = kc * 32 + lk * 8 + e;
        wh[e] = (short)f2bf(WH[k * G4_ + col] * scl);
      }
      bWh[g][kc] = wh;
    }
  }

  // fp32 state: 2 rows per lane
  float c[2], hn[2];
  c[0]  = ST[(doff2 + 0) * U_ + uu];
  c[1]  = ST[(doff2 + 1) * U_ + uu];
  hn[0] = ST[(B_ + doff2 + 0) * U_ + uu];
  hn[1] = ST[(B_ + doff2 + 1) * U_ + uu];
  { // mask m(0), publish to real+mirror slots
    f32x2 d2 = *(const f32x2*)&DN[doff2];
    const float m0 = 1.0f - d2[0], m1 = 1.0f - d2[1];
    c[0] *= m0; c[1] *= m1;
    const unsigned pk = cvt_pk_bf16(hn[0] * m0, hn[1] * m1);
    hbuf[0][hA0] = (short)pk;          hbuf[0][hB0] = (short)pk;
    hbuf[0][hA1] = (short)(pk >> 16);  hbuf[0][hB1] = (short)(pk >> 16);
  }

  // zx thread-const offset into R4 identity layout (pads duplicate real addresses)
  const int bt  = blockIdx.x >> 1;
  const int lkw = (blockIdx.x & 1) * 2 + lkm;
  const int zoff = ((bt * 8 + w) * 64 + lkw * 16 + lr) * 16;

  f32x4 zxA[4], zxB[4];
  f32x2 dv;
#pragma unroll
  for (int g = 0; g < 4; ++g) zxA[g] = *(const f32x4*)(ZX + zoff + g * 4);
#pragma unroll
  for (int g = 0; g < 4; ++g) zxB[g] = *(const f32x4*)(ZX + ZSTRIDE + zoff + g * 4);
  dv = *(const f32x2*)&DN[B_ + doff2];
  sync_lds();  // h(0) visible

  // step: tz/td/to are loop-uniform element offsets (SGPR-side stepping)
  auto step = [&](const int p, const bool pub, const bool pre, f32x4 (&zxC)[4],
                  const int tz, const int td, const int to) {
    // a) h(t) fragments from swizzled LDS
    s16x8 ah[4];
#pragma unroll
    for (int kc = 0; kc < 4; ++kc) {
      const int sl = (kc * 4 + lk) ^ lr;
      ah[kc] = *(const s16x8*)&hbuf[p][lr * U_ + sl * 8];
    }
    // b) z = zx + h @ Wh (prefetched zx regs ARE the C-init)
    f32x4 az[4];
#pragma unroll
    for (int g = 0; g < 4; ++g) {
      f32x4 a = zxC[g];
#pragma unroll
      for (int kc = 0; kc < 4; ++kc)
        a = __builtin_amdgcn_mfma_f32_16x16x32_bf16(ah[kc], bWh[g][kc], a, 0, 0, 0);
      az[g] = a;
    }
    // c) refill zx(t+2) — uniform base + const voffset
    if (pre) {
#pragma unroll
      for (int g = 0; g < 4; ++g) zxC[g] = *(const f32x4*)(ZX + tz + zoff + g * 4);
    }
    // d) activations for this lane's 2 rows (bare v_exp_f32; z pre-scaled by log2e)
#pragma unroll
    for (int j = 0; j < 2; ++j) {
      const int r = r0 + j;
      const float eA = EXP2(-az[0][r]);
      const float eC = EXP2(-az[1][r]);
      const float eD = EXP2(-az[2][r]);
      const float eB = EXP2(-az[3][r]);
      const float iu = (1.0f - eB) * __builtin_amdgcn_rcpf((1.0f + eA) * (1.0f + eB));
      const float fg = __builtin_amdgcn_rcpf(1.0f + eC);
      const float cn = fmaf(fg, c[j], iu);
      const float ce = fminf(fmaxf(cn, -15.0f), 15.0f);
      const float eE = EXP2(ce * (-2.0f * L2E));
      const float h  = (1.0f - eE) * __builtin_amdgcn_rcpf((1.0f + eD) * (1.0f + eE));
      c[j]  = cn;
      hn[j] = h;
      OUT[to + ooff2 + j * U_] = h;
    }
    // e) dones for t+1 (held), issue d(t+2)
    f32x2 dcur = dv;
    if (pre) dv = *(const f32x2*)(DN + td + doff2);
    // f) mask m(t+1), publish to real+mirror slots (no cross-lane exchange)
    if (pub) {
      const float m0 = 1.0f - dcur[0], m1 = 1.0f - dcur[1];
      c[0] *= m0; c[1] *= m1;
      const unsigned pk = cvt_pk_bf16(hn[0] * m0, hn[1] * m1);
      short* hb = hbuf[p ^ 1];
      hb[hA0] = (short)pk;          hb[hB0] = (short)pk;
      hb[hA1] = (short)(pk >> 16);  hb[hB1] = (short)(pk >> 16);
    }
    sync_lds();
  };

  for (int t = 0; t < T_; t += 2) {
    step(0, true, t + 2 < T_, zxA,
         (t + 2) * ZSTRIDE, (t + 2) * B_, t * (B_ * U_));
    step(1, t + 2 < T_, t + 3 < T_, zxB,
         (t + 3) * ZSTRIDE, (t + 3) * B_, (t + 1) * (B_ * U_));
  }

  // final carry (c, h) after step T-1, unmasked — 2 rows per lane, all lanes
  const long fb = (long)T_ * B_ * U_;
#pragma unroll
  for (int j = 0; j < 2; ++j) {
    OUT[fb + (long)(doff2 + j) * U_ + uu]                 = c[j];
    OUT[fb + (long)B_ * U_ + (long)(doff2 + j) * U_ + uu] = hn[j];
  }
}

// ============ fallback (R3 kernel verbatim): used when ws is too small ============
__global__ __launch_bounds__(512, 1)
void lstm_fb_kernel(const float* __restrict__ X, const float* __restrict__ ST,
                    const float* __restrict__ DN, const float* __restrict__ WX,
                    const float* __restrict__ WH, float* __restrict__ OUT)
{
  __shared__ __align__(16) short hbuf[2][16 * U_];

  const int tid  = threadIdx.x;
  const int w    = tid >> 6;
  const int lane = tid & 63;
  const int lr   = lane & 15;
  const int lk   = lane >> 4;
  const int b0   = blockIdx.x * 16;
  const int row0 = lk * 4;
  const int uu   = w * 16 + lr;

  const int xoff = (b0 + lr) * F_ + lk * 8;
  const int doff = b0 + row0;
  const int ooff = (b0 + row0) * U_ + uu;

  s16x8 bWh[4][4], bWx[4][4];
#pragma unroll
  for (int g = 0; g < 4; ++g) {
    const int col = g * 128 + uu;
#pragma unroll
    for (int kc = 0; kc < 4; ++kc) {
      s16x8 wh, wx;
#pragma unroll
      for (int e = 0; e < 8; ++e) {
        const int k = kc * 32 + lk * 8 + e;
        wh[e] = (short)f2bf(WH[k * G4_ + col]);
        wx[e] = (short)f2bf(WX[k * G4_ + col]);
      }
      bWh[g][kc] = wh;
      bWx[g][kc] = wx;
    }
  }

  float c[4], hn[4];
#pragma unroll
  for (int r = 0; r < 4; ++r) {
    c[r]  = ST[(b0 + row0 + r) * U_ + uu];
    hn[r] = ST[(B_ + b0 + row0 + r) * U_ + uu];
  }
  {
    f32x4 d = *(const f32x4*)&DN[doff];
#pragma unroll
    for (int r = 0; r < 4; ++r) {
      const float m = 1.0f - d[r];
      c[r] *= m;
      const int row = row0 + r;
      const int sl  = (uu >> 3) ^ row;
      hbuf[0][row * U_ + sl * 8 + (uu & 7)] = (short)cvt_pk_bf16(hn[r] * m, 0.f);
    }
  }

  f32x4 xv0[4], xv1[4], dv;
  f32x4 accA[4], accB[4];
  {
    const float* xp = X + xoff;
    s16x8 xa[4];
#pragma unroll
    for (int kc = 0; kc < 4; ++kc)
      xa[kc] = pack8(*(const f32x4*)(xp + kc * 32), *(const f32x4*)(xp + kc * 32 + 4));
#pragma unroll
    for (int g = 0; g < 4; ++g) {
      f32x4 a = {0.f, 0.f, 0.f, 0.f};
#pragma unroll
      for (int kc = 0; kc < 4; ++kc)
        a = __builtin_amdgcn_mfma_f32_16x16x32_bf16(xa[kc], bWx[g][kc], a, 0, 0, 0);
      accA[g] = a;
    }
#pragma unroll
    for (int kc = 0; kc < 4; ++kc) {
      xv0[kc] = *(const f32x4*)(X + B_ * F_ + xoff + kc * 32);
      xv1[kc] = *(const f32x4*)(X + B_ * F_ + xoff + kc * 32 + 4);
    }
    dv = *(const f32x4*)(DN + B_ + doff);
  }
  sync_lds();

  const float* Xt  = X + 2 * B_ * F_;
  const float* DNt = DN + 2 * B_;
  float*       Ot  = OUT;

  auto step = [&](const int p, const bool act_x, const bool pre_x,
                  f32x4 (&accZ)[4], f32x4 (&accX)[4]) {
    s16x8 ah[4];
#pragma unroll
    for (int kc = 0; kc < 4; ++kc) {
      const int sl = (kc * 4 + lk) ^ lr;
      ah[kc] = *(const s16x8*)&hbuf[p][lr * U_ + sl * 8];
    }
#pragma unroll
    for (int g = 0; g < 4; ++g) {
      f32x4 a = accZ[g];
#pragma unroll
      for (int kc = 0; kc < 4; ++kc)
        a = __builtin_amdgcn_mfma_f32_16x16x32_bf16(ah[kc], bWh[g][kc], a, 0, 0, 0);
      accZ[g] = a;
    }
#pragma unroll
    for (int r = 0; r < 4; ++r) {
      const float eA = __expf(-accZ[0][r]);
      const float eB = __expf(-2.0f * accZ[3][r]);
      const float eC = __expf(-accZ[1][r]);
      const float eD = __expf(-accZ[2][r]);
      const float iu = (1.0f - eB) * __builtin_amdgcn_rcpf((1.0f + eA) * (1.0f + eB));
      const float fg = __builtin_amdgcn_rcpf(1.0f + eC);
      const float cn = fmaf(fg, c[r], iu);
      const float ce = fminf(fmaxf(cn, -30.0f), 30.0f);
      const float eE = __expf(-2.0f * ce);
      const float h  = (1.0f - eE) * __builtin_amdgcn_rcpf((1.0f + eD) * (1.0f + eE));
      c[r]  = cn;
      hn[r] = h;
      Ot[ooff + r * U_] = h;
    }
    if (act_x) {
      s16x8 xa[4];
#pragma unroll
      for (int kc = 0; kc < 4; ++kc) xa[kc] = pack8(xv0[kc], xv1[kc]);
#pragma unroll
      for (int g = 0; g < 4; ++g) {
        f32x4 a = {0.f, 0.f, 0.f, 0.f};
#pragma unroll
        for (int kc = 0; kc < 4; ++kc)
          a = __builtin_amdgcn_mfma_f32_16x16x32_bf16(xa[kc], bWx[g][kc], a, 0, 0, 0);
        accX[g] = a;
      }
    }
    f32x4 dcur = dv;
    if (pre_x) {
#pragma unroll
      for (int kc = 0; kc < 4; ++kc) {
        xv0[kc] = *(const f32x4*)(Xt + xoff + kc * 32);
        xv1[kc] = *(const f32x4*)(Xt + xoff + kc * 32 + 4);
      }
      dv = *(const f32x4*)(DNt + doff);
    }
    if (act_x) {
#pragma unroll
      for (int r = 0; r < 4; ++r) {
        const float m = 1.0f - dcur[r];
        c[r] *= m;
        const int row = row0 + r;
        const int sl  = (uu >> 3) ^ row;
        hbuf[p ^ 1][row * U_ + sl * 8 + (uu & 7)] = (short)cvt_pk_bf16(hn[r] * m, 0.f);
      }
    }
    sync_lds();
  };

  for (int t = 0; t < T_; t += 2) {
    step(0, true, t + 2 < T_, accA, accB);
    Xt += B_ * F_; DNt += B_; Ot += B_ * U_;
    step(1, t + 2 < T_, t + 3 < T_, accB, accA);
    Xt += B_ * F_; DNt += B_; Ot += B_ * U_;
  }

  const long fb = (long)T_ * B_ * U_;
#pragma unroll
  for (int r = 0; r < 4; ++r) {
    OUT[fb + (long)(b0 + row0 + r) * U_ + uu]                 = c[r];
    OUT[fb + (long)B_ * U_ + (long)(b0 + row0 + r) * U_ + uu] = hn[r];
  }
}

extern "C" void kernel_launch(void* const* d_in, const int* in_sizes, int n_in,
                              void* d_out, int out_size, void* d_ws, size_t ws_size,
                              hipStream_t stream) {
  const float* X  = (const float*)d_in[0];  // [T,B,F]
  const float* ST = (const float*)d_in[1];  // [2,B,U]
  const float* DN = (const float*)d_in[2];  // [T,B]
  const float* WX = (const float*)d_in[3];  // [F,4U]
  const float* WH = (const float*)d_in[4];  // [U,4U]
  float* OUT = (float*)d_out;               // [T*B*U + 2*B*U]

  if (ws_size >= ZX_BYTES) {
    float* ZX = (float*)d_ws;
    zx_gemm_kernel<<<dim3(256), dim3(512), 0, stream>>>(X, WX, ZX);
    lstm_zx32v_kernel<<<dim3(NBLK), dim3(512), 0, stream>>>(ZX, ST, DN, WH, OUT);
  } else {
    lstm_fb_kernel<<<dim3(16), dim3(512), 0, stream>>>(X, ST, DN, WX, WH, OUT);
  }
}

// Round 10
// 460.770 us; speedup vs baseline: 3.3383x; 1.3409x over previous
//
#include <hip/hip_runtime.h>

#define T_  512
#define B_  256
#define F_  128
#define U_  128
#define G4_ 512
#define L2E 1.4426950408889634f
#define NBLK 32                              // recurrent blocks (8 real rows each)
#define ZSTR8 (16 * 512 * 8)                 // zx-bf16 dwords per timestep
#define ZB_BYTES ((size_t)T_ * B_ * G4_ * 2) // 134217728

using f32x4 = __attribute__((ext_vector_type(4))) float;
using f32x2 = __attribute__((ext_vector_type(2))) float;
using s16x8 = __attribute__((ext_vector_type(8))) short;
using u32x4 = __attribute__((ext_vector_type(4))) unsigned int;

#if __has_builtin(__builtin_amdgcn_exp2f)
#define EXP2(x) __builtin_amdgcn_exp2f(x)    // bare v_exp_f32, no libcall
#else
#define EXP2(x) exp2f(x)
#endif

__device__ __forceinline__ unsigned fbits(float f) { return __builtin_bit_cast(unsigned, f); }
__device__ __forceinline__ float bitsf(unsigned u) { return __builtin_bit_cast(float, u); }

// pure-C RNE fp32->bf16 (verified on weights since R1; NO inline asm)
__device__ __forceinline__ unsigned short f2bf(float f) {
  unsigned u = fbits(f);
  u += 0x7FFFu + ((u >> 16) & 1u);
  return (unsigned short)(u >> 16);
}
// hardware RNE pack (verified: h-publish R7/R8, pack8 R3+) — used on VALU values only
__device__ __forceinline__ unsigned cvt_pk_bf16(float lo, float hi) {
  unsigned r;
  asm("v_cvt_pk_bf16_f32 %0, %1, %2" : "=v"(r) : "v"(lo), "v"(hi));
  return r;
}
__device__ __forceinline__ s16x8 pack8(f32x4 a, f32x4 b) {
  u32x4 w;
  w[0] = cvt_pk_bf16(a[0], a[1]);
  w[1] = cvt_pk_bf16(a[2], a[3]);
  w[2] = cvt_pk_bf16(b[0], b[1]);
  w[3] = cvt_pk_bf16(b[2], b[3]);
  return __builtin_bit_cast(s16x8, w);
}
// barrier waiting only on LDS ops — global loads/stores stay in flight
__device__ __forceinline__ void sync_lds() {
  asm volatile("s_waitcnt lgkmcnt(0)\n\ts_barrier" ::: "memory");
}

// ====== kernel 1: zx = bf16(X @ (Wx*scale)) — R4 structure VERBATIM, store block only
// changed: pure-C f2bf pack, per-gate immediate store (no acc array, no asm on acc).
// Dword index: ((G*8 + wave)*64 + lane)*8 + g*2 + half; half0 = (r1<<16)|r0, half1 = (r3<<16)|r2.
__global__ __launch_bounds__(512, 1)
void zxb_gemm_kernel(const float* __restrict__ X, const float* __restrict__ WX,
                     unsigned* __restrict__ ZB)
{
  const int tid  = threadIdx.x;
  const int w    = tid >> 6;
  const int lane = tid & 63;
  const int lr   = lane & 15;
  const int lk   = lane >> 4;

  s16x8 bWx[4][4];
#pragma unroll
  for (int g = 0; g < 4; ++g) {
    const float scl = (g == 3) ? 2.0f * L2E : L2E;   // u-gate carries tanh's 2x
    const int col = g * 128 + w * 16 + lr;
#pragma unroll
    for (int kc = 0; kc < 4; ++kc) {
      s16x8 wx;
#pragma unroll
      for (int e = 0; e < 8; ++e) {
        const int k = kc * 32 + lk * 8 + e;
        wx[e] = (short)f2bf(WX[k * G4_ + col] * scl);
      }
      bWx[g][kc] = wx;
    }
  }

  const int G0 = blockIdx.x * 32;
  const float* xp = X + (size_t)(G0 * 16 + lr) * F_ + lk * 8;
  unsigned*    zp = ZB + ((size_t)(G0 * 8 + w) * 64 + lane) * 8;

  for (int grp = 0; grp < 32; ++grp) {
    s16x8 xa[4];
#pragma unroll
    for (int kc = 0; kc < 4; ++kc)
      xa[kc] = pack8(*(const f32x4*)(xp + kc * 32), *(const f32x4*)(xp + kc * 32 + 4));
#pragma unroll
    for (int g = 0; g < 4; ++g) {
      f32x4 a = {0.f, 0.f, 0.f, 0.f};
#pragma unroll
      for (int kc = 0; kc < 4; ++kc)
        a = __builtin_amdgcn_mfma_f32_16x16x32_bf16(xa[kc], bWx[g][kc], a, 0, 0, 0);
      // pure-C RNE pack of the acc, stored immediately (R4's per-g store shape)
      const unsigned p0 = ((unsigned)f2bf(a[1]) << 16) | (unsigned)f2bf(a[0]);
      const unsigned p1 = ((unsigned)f2bf(a[3]) << 16) | (unsigned)f2bf(a[2]);
      zp[g * 2]     = p0;
      zp[g * 2 + 1] = p1;
    }
    xp += 16 * F_;
    zp += 8 * 64 * 8;
  }
}

// ====== kernel 2: R8 structure verbatim; zx loads bf16-packed (x8 dwords) + bit-decode ======
__global__ __launch_bounds__(512, 1)
void lstm_zxb_kernel(const unsigned* __restrict__ ZB, const float* __restrict__ ST,
                     const float* __restrict__ DN, const float* __restrict__ WH,
                     float* __restrict__ OUT)
{
  __shared__ __align__(16) short hbuf[2][16 * U_];

  const int tid  = threadIdx.x;
  const int w    = tid >> 6;
  const int lane = tid & 63;
  const int lr   = lane & 15;
  const int lk   = lane >> 4;
  const int lkm  = lk & 1;            // mirrored row-group select
  const int r0   = (lk >> 1) * 2;     // owned az rows: r0, r0+1
  const int b0   = blockIdx.x * 8;
  const int wr0  = lkm * 4 + r0;      // owned real row (0..7)
  const int uu   = w * 16 + lr;

  const int doff2 = b0 + wr0;                    // this lane's 2 dones
  const int ooff2 = (b0 + wr0) * U_ + uu;        // this lane's 2 OUT rows

  // hbuf addresses (shorts), thread-constant: real rows wr0,wr0+1 and mirrors +8
  const int hA0 = (wr0 + 0) * U_ + ((((uu >> 3) ^ (wr0 + 0)) & 15) * 8) + (uu & 7);
  const int hA1 = (wr0 + 1) * U_ + ((((uu >> 3) ^ (wr0 + 1)) & 15) * 8) + (uu & 7);
  const int hB0 = (wr0 + 8) * U_ + ((((uu >> 3) ^ (wr0 + 8)) & 15) * 8) + (uu & 7);
  const int hB1 = (wr0 + 9) * U_ + ((((uu >> 3) ^ (wr0 + 9)) & 15) * 8) + (uu & 7);

  // Wh, pre-scaled per gate (log2e; 2*log2e for u)
  s16x8 bWh[4][4];
#pragma unroll
  for (int g = 0; g < 4; ++g) {
    const float scl = (g == 3) ? 2.0f * L2E : L2E;
    const int col = g * 128 + uu;
#pragma unroll
    for (int kc = 0; kc < 4; ++kc) {
      s16x8 wh;
#pragma unroll
      for (int e = 0; e < 8; ++e) {
        const int k = kc * 32 + lk * 8 + e;
        wh[e] = (short)f2bf(WH[k * G4_ + col] * scl);
      }
      bWh[g][kc] = wh;
    }
  }

  // fp32 state: 2 rows per lane
  float c[2], hn[2];
  c[0]  = ST[(doff2 + 0) * U_ + uu];
  c[1]  = ST[(doff2 + 1) * U_ + uu];
  hn[0] = ST[(B_ + doff2 + 0) * U_ + uu];
  hn[1] = ST[(B_ + doff2 + 1) * U_ + uu];
  { // mask m(0), publish to real+mirror slots
    f32x2 d2 = *(const f32x2*)&DN[doff2];
    const float m0 = 1.0f - d2[0], m1 = 1.0f - d2[1];
    c[0] *= m0; c[1] *= m1;
    const unsigned pk = cvt_pk_bf16(hn[0] * m0, hn[1] * m1);
    hbuf[0][hA0] = (short)pk;          hbuf[0][hB0] = (short)pk;
    hbuf[0][hA1] = (short)(pk >> 16);  hbuf[0][hB1] = (short)(pk >> 16);
  }

  // zx thread-const dword offset into packed identity layout (pads duplicate reals)
  const int bt  = blockIdx.x >> 1;
  const int lkw = (blockIdx.x & 1) * 2 + lkm;
  const int zoff = ((bt * 8 + w) * 64 + lkw * 16 + lr) * 8;

  u32x4 zA0, zA1, zB0, zB1;
  f32x2 dv;
  zA0 = *(const u32x4*)(ZB + zoff);
  zA1 = *(const u32x4*)(ZB + zoff + 4);
  zB0 = *(const u32x4*)(ZB + ZSTR8 + zoff);
  zB1 = *(const u32x4*)(ZB + ZSTR8 + zoff + 4);
  dv = *(const f32x2*)&DN[B_ + doff2];
  sync_lds();  // h(0) visible

  // step: tz/td/to are loop-uniform element offsets (SGPR-side stepping)
  auto step = [&](const int p, const bool pub, const bool pre,
                  u32x4& zq0, u32x4& zq1, const int tz, const int td, const int to) {
    // a) h(t) fragments from swizzled LDS
    s16x8 ah[4];
#pragma unroll
    for (int kc = 0; kc < 4; ++kc) {
      const int sl = (kc * 4 + lk) ^ lr;
      ah[kc] = *(const s16x8*)&hbuf[p][lr * U_ + sl * 8];
    }
    // b) decode bf16 zx -> f32 C-init (== R1's verified bf2f bit-op), z = zx + h@Wh
    f32x4 az[4];
#pragma unroll
    for (int g = 0; g < 4; ++g) {
      const unsigned d0 = (g < 2) ? zq0[(g & 1) * 2]     : zq1[(g & 1) * 2];
      const unsigned d1 = (g < 2) ? zq0[(g & 1) * 2 + 1] : zq1[(g & 1) * 2 + 1];
      f32x4 a = { bitsf(d0 << 16), bitsf(d0 & 0xFFFF0000u),
                  bitsf(d1 << 16), bitsf(d1 & 0xFFFF0000u) };
#pragma unroll
      for (int kc = 0; kc < 4; ++kc)
        a = __builtin_amdgcn_mfma_f32_16x16x32_bf16(ah[kc], bWh[g][kc], a, 0, 0, 0);
      az[g] = a;
    }
    // c) refill zx(t+2) — uniform base + const voffset
    if (pre) {
      zq0 = *(const u32x4*)(ZB + tz + zoff);
      zq1 = *(const u32x4*)(ZB + tz + zoff + 4);
    }
    // d) activations for this lane's 2 rows (bare v_exp_f32; z pre-scaled by log2e)
#pragma unroll
    for (int j = 0; j < 2; ++j) {
      const int r = r0 + j;
      const float eA = EXP2(-az[0][r]);
      const float eC = EXP2(-az[1][r]);
      const float eD = EXP2(-az[2][r]);
      const float eB = EXP2(-az[3][r]);
      const float iu = (1.0f - eB) * __builtin_amdgcn_rcpf((1.0f + eA) * (1.0f + eB));
      const float fg = __builtin_amdgcn_rcpf(1.0f + eC);
      const float cn = fmaf(fg, c[j], iu);
      const float ce = fminf(fmaxf(cn, -15.0f), 15.0f);
      const float eE = EXP2(ce * (-2.0f * L2E));
      const float h  = (1.0f - eE) * __builtin_amdgcn_rcpf((1.0f + eD) * (1.0f + eE));
      c[j]  = cn;
      hn[j] = h;
      OUT[to + ooff2 + j * U_] = h;
    }
    // e) dones for t+1 (held), issue d(t+2)
    f32x2 dcur = dv;
    if (pre) dv = *(const f32x2*)(DN + td + doff2);
    // f) mask m(t+1), publish to real+mirror slots (no cross-lane exchange)
    if (pub) {
      const float m0 = 1.0f - dcur[0], m1 = 1.0f - dcur[1];
      c[0] *= m0; c[1] *= m1;
      const unsigned pk = cvt_pk_bf16(hn[0] * m0, hn[1] * m1);
      short* hb = hbuf[p ^ 1];
      hb[hA0] = (short)pk;          hb[hB0] = (short)pk;
      hb[hA1] = (short)(pk >> 16);  hb[hB1] = (short)(pk >> 16);
    }
    sync_lds();
  };

  for (int t = 0; t < T_; t += 2) {
    step(0, true, t + 2 < T_, zA0, zA1,
         (t + 2) * ZSTR8, (t + 2) * B_, t * (B_ * U_));
    step(1, t + 2 < T_, t + 3 < T_, zB0, zB1,
         (t + 3) * ZSTR8, (t + 3) * B_, (t + 1) * (B_ * U_));
  }

  // final carry (c, h) after step T-1, unmasked — 2 rows per lane, all lanes
  const long fb = (long)T_ * B_ * U_;
#pragma unroll
  for (int j = 0; j < 2; ++j) {
    OUT[fb + (long)(doff2 + j) * U_ + uu]                 = c[j];
    OUT[fb + (long)B_ * U_ + (long)(doff2 + j) * U_ + uu] = hn[j];
  }
}

// ============ fallback (R3 kernel verbatim): used when ws is too small ============
__global__ __launch_bounds__(512, 1)
void lstm_fb_kernel(const float* __restrict__ X, const float* __restrict__ ST,
                    const float* __restrict__ DN, const float* __restrict__ WX,
                    const float* __restrict__ WH, float* __restrict__ OUT)
{
  __shared__ __align__(16) short hbuf[2][16 * U_];

  const int tid  = threadIdx.x;
  const int w    = tid >> 6;
  const int lane = tid & 63;
  const int lr   = lane & 15;
  const int lk   = lane >> 4;
  const int b0   = blockIdx.x * 16;
  const int row0 = lk * 4;
  const int uu   = w * 16 + lr;

  const int xoff = (b0 + lr) * F_ + lk * 8;
  const int doff = b0 + row0;
  const int ooff = (b0 + row0) * U_ + uu;

  s16x8 bWh[4][4], bWx[4][4];
#pragma unroll
  for (int g = 0; g < 4; ++g) {
    const int col = g * 128 + uu;
#pragma unroll
    for (int kc = 0; kc < 4; ++kc) {
      s16x8 wh, wx;
#pragma unroll
      for (int e = 0; e < 8; ++e) {
        const int k = kc * 32 + lk * 8 + e;
        wh[e] = (short)f2bf(WH[k * G4_ + col]);
        wx[e] = (short)f2bf(WX[k * G4_ + col]);
      }
      bWh[g][kc] = wh;
      bWx[g][kc] = wx;
    }
  }

  float c[4], hn[4];
#pragma unroll
  for (int r = 0; r < 4; ++r) {
    c[r]  = ST[(b0 + row0 + r) * U_ + uu];
    hn[r] = ST[(B_ + b0 + row0 + r) * U_ + uu];
  }
  {
    f32x4 d = *(const f32x4*)&DN[doff];
#pragma unroll
    for (int r = 0; r < 4; ++r) {
      const float m = 1.0f - d[r];
      c[r] *= m;
      const int row = row0 + r;
      const int sl  = (uu >> 3) ^ row;
      hbuf[0][row * U_ + sl * 8 + (uu & 7)] = (short)cvt_pk_bf16(hn[r] * m, 0.f);
    }
  }

  f32x4 xv0[4], xv1[4], dv;
  f32x4 accA[4], accB[4];
  {
    const float* xp = X + xoff;
    s16x8 xa[4];
#pragma unroll
    for (int kc = 0; kc < 4; ++kc)
      xa[kc] = pack8(*(const f32x4*)(xp + kc * 32), *(const f32x4*)(xp + kc * 32 + 4));
#pragma unroll
    for (int g = 0; g < 4; ++g) {
      f32x4 a = {0.f, 0.f, 0.f, 0.f};
#pragma unroll
      for (int kc = 0; kc < 4; ++kc)
        a = __builtin_amdgcn_mfma_f32_16x16x32_bf16(xa[kc], bWx[g][kc], a, 0, 0, 0);
      accA[g] = a;
    }
#pragma unroll
    for (int kc = 0; kc < 4; ++kc) {
      xv0[kc] = *(const f32x4*)(X + B_ * F_ + xoff + kc * 32);
      xv1[kc] = *(const f32x4*)(X + B_ * F_ + xoff + kc * 32 + 4);
    }
    dv = *(const f32x4*)(DN + B_ + doff);
  }
  sync_lds();

  const float* Xt  = X + 2 * B_ * F_;
  const float* DNt = DN + 2 * B_;
  float*       Ot  = OUT;

  auto step = [&](const int p, const bool act_x, const bool pre_x,
                  f32x4 (&accZ)[4], f32x4 (&accX)[4]) {
    s16x8 ah[4];
#pragma unroll
    for (int kc = 0; kc < 4; ++kc) {
      const int sl = (kc * 4 + lk) ^ lr;
      ah[kc] = *(const s16x8*)&hbuf[p][lr * U_ + sl * 8];
    }
#pragma unroll
    for (int g = 0; g < 4; ++g) {
      f32x4 a = accZ[g];
#pragma unroll
      for (int kc = 0; kc < 4; ++kc)
        a = __builtin_amdgcn_mfma_f32_16x16x32_bf16(ah[kc], bWh[g][kc], a, 0, 0, 0);
      accZ[g] = a;
    }
#pragma unroll
    for (int r = 0; r < 4; ++r) {
      const float eA = __expf(-accZ[0][r]);
      const float eB = __expf(-2.0f * accZ[3][r]);
      const float eC = __expf(-accZ[1][r]);
      const float eD = __expf(-accZ[2][r]);
      const float iu = (1.0f - eB) * __builtin_amdgcn_rcpf((1.0f + eA) * (1.0f + eB));
      const float fg = __builtin_amdgcn_rcpf(1.0f + eC);
      const float cn = fmaf(fg, c[r], iu);
      const float ce = fminf(fmaxf(cn, -30.0f), 30.0f);
      const float eE = __expf(-2.0f * ce);
      const float h  = (1.0f - eE) * __builtin_amdgcn_rcpf((1.0f + eD) * (1.0f + eE));
      c[r]  = cn;
      hn[r] = h;
      Ot[ooff + r * U_] = h;
    }
    if (act_x) {
      s16x8 xa[4];
#pragma unroll
      for (int kc = 0; kc < 4; ++kc) xa[kc] = pack8(xv0[kc], xv1[kc]);
#pragma unroll
      for (int g = 0; g < 4; ++g) {
        f32x4 a = {0.f, 0.f, 0.f, 0.f};
#pragma unroll
        for (int kc = 0; kc < 4; ++kc)
          a = __builtin_amdgcn_mfma_f32_16x16x32_bf16(xa[kc], bWx[g][kc], a, 0, 0, 0);
        accX[g] = a;
      }
    }
    f32x4 dcur = dv;
    if (pre_x) {
#pragma unroll
      for (int kc = 0; kc < 4; ++kc) {
        xv0[kc] = *(const f32x4*)(Xt + xoff + kc * 32);
        xv1[kc] = *(const f32x4*)(Xt + xoff + kc * 32 + 4);
      }
      dv = *(const f32x4*)(DNt + doff);
    }
    if (act_x) {
#pragma unroll
      for (int r = 0; r < 4; ++r) {
        const float m = 1.0f - dcur[r];
        c[r] *= m;
        const int row = row0 + r;
        const int sl  = (uu >> 3) ^ row;
        hbuf[p ^ 1][row * U_ + sl * 8 + (uu & 7)] = (short)cvt_pk_bf16(hn[r] * m, 0.f);
      }
    }
    sync_lds();
  };

  for (int t = 0; t < T_; t += 2) {
    step(0, true, t + 2 < T_, accA, accB);
    Xt += B_ * F_; DNt += B_; Ot += B_ * U_;
    step(1, t + 2 < T_, t + 3 < T_, accB, accA);
    Xt += B_ * F_; DNt += B_; Ot += B_ * U_;
  }

  const long fb = (long)T_ * B_ * U_;
#pragma unroll
  for (int r = 0; r < 4; ++r) {
    OUT[fb + (long)(b0 + row0 + r) * U_ + uu]                 = c[r];
    OUT[fb + (long)B_ * U_ + (long)(b0 + row0 + r) * U_ + uu] = hn[r];
  }
}

extern "C" void kernel_launch(void* const* d_in, const int* in_sizes, int n_in,
                              void* d_out, int out_size, void* d_ws, size_t ws_size,
                              hipStream_t stream) {
  const float* X  = (const float*)d_in[0];  // [T,B,F]
  const float* ST = (const float*)d_in[1];  // [2,B,U]
  const float* DN = (const float*)d_in[2];  // [T,B]
  const float* WX = (const float*)d_in[3];  // [F,4U]
  const float* WH = (const float*)d_in[4];  // [U,4U]
  float* OUT = (float*)d_out;               // [T*B*U + 2*B*U]

  if (ws_size >= ZB_BYTES) {
    unsigned* ZB = (unsigned*)d_ws;
    zxb_gemm_kernel<<<dim3(256), dim3(512), 0, stream>>>(X, WX, ZB);
    lstm_zxb_kernel<<<dim3(NBLK), dim3(512), 0, stream>>>(ZB, ST, DN, WH, OUT);
  } else {
    lstm_fb_kernel<<<dim3(16), dim3(512), 0, stream>>>(X, ST, DN, WX, WH, OUT);
  }
}

// Round 11
// 416.205 us; speedup vs baseline: 3.6958x; 1.1071x over previous
//
#include <hip/hip_runtime.h>

#define T_  512
#define B_  256
#define F_  128
#define U_  128
#define G4_ 512
#define L2E 1.4426950408889634f
#define NBLK 64                              // recurrent blocks (4 real rows each)
#define ZSTR8 (16 * 512 * 8)                 // zx-bf16 dwords per timestep
#define ZB_BYTES ((size_t)T_ * B_ * G4_ * 2) // 134217728

using f32x4 = __attribute__((ext_vector_type(4))) float;
using f32x2 = __attribute__((ext_vector_type(2))) float;
using s16x8 = __attribute__((ext_vector_type(8))) short;
using u32x4 = __attribute__((ext_vector_type(4))) unsigned int;

#if __has_builtin(__builtin_amdgcn_exp2f)
#define EXP2(x) __builtin_amdgcn_exp2f(x)    // bare v_exp_f32, no libcall
#else
#define EXP2(x) exp2f(x)
#endif

__device__ __forceinline__ unsigned fbits(float f) { return __builtin_bit_cast(unsigned, f); }
__device__ __forceinline__ float bitsf(unsigned u) { return __builtin_bit_cast(float, u); }

// pure-C RNE fp32->bf16 (verified since R1; NO inline asm)
__device__ __forceinline__ unsigned short f2bf(float f) {
  unsigned u = fbits(f);
  u += 0x7FFFu + ((u >> 16) & 1u);
  return (unsigned short)(u >> 16);
}
// hardware RNE pack — used on VALU/loaded values only (never on MFMA acc: R9 lesson)
__device__ __forceinline__ unsigned cvt_pk_bf16(float lo, float hi) {
  unsigned r;
  asm("v_cvt_pk_bf16_f32 %0, %1, %2" : "=v"(r) : "v"(lo), "v"(hi));
  return r;
}
__device__ __forceinline__ s16x8 pack8(f32x4 a, f32x4 b) {
  u32x4 w;
  w[0] = cvt_pk_bf16(a[0], a[1]);
  w[1] = cvt_pk_bf16(a[2], a[3]);
  w[2] = cvt_pk_bf16(b[0], b[1]);
  w[3] = cvt_pk_bf16(b[2], b[3]);
  return __builtin_bit_cast(s16x8, w);
}
// barrier waiting only on LDS ops — global loads/stores stay in flight
__device__ __forceinline__ void sync_lds() {
  asm volatile("s_waitcnt lgkmcnt(0)\n\ts_barrier" ::: "memory");
}

// ====== kernel 1 (VERBATIM R10, known-good): zx = bf16(X @ (Wx*scale)) ======
// Dword index: ((G*8 + wave)*64 + lane)*8 + g*2 + half; half0 = (r1<<16)|r0, half1 = (r3<<16)|r2.
__global__ __launch_bounds__(512, 1)
void zxb_gemm_kernel(const float* __restrict__ X, const float* __restrict__ WX,
                     unsigned* __restrict__ ZB)
{
  const int tid  = threadIdx.x;
  const int w    = tid >> 6;
  const int lane = tid & 63;
  const int lr   = lane & 15;
  const int lk   = lane >> 4;

  s16x8 bWx[4][4];
#pragma unroll
  for (int g = 0; g < 4; ++g) {
    const float scl = (g == 3) ? 2.0f * L2E : L2E;   // u-gate carries tanh's 2x
    const int col = g * 128 + w * 16 + lr;
#pragma unroll
    for (int kc = 0; kc < 4; ++kc) {
      s16x8 wx;
#pragma unroll
      for (int e = 0; e < 8; ++e) {
        const int k = kc * 32 + lk * 8 + e;
        wx[e] = (short)f2bf(WX[k * G4_ + col] * scl);
      }
      bWx[g][kc] = wx;
    }
  }

  const int G0 = blockIdx.x * 32;
  const float* xp = X + (size_t)(G0 * 16 + lr) * F_ + lk * 8;
  unsigned*    zp = ZB + ((size_t)(G0 * 8 + w) * 64 + lane) * 8;

  for (int grp = 0; grp < 32; ++grp) {
    s16x8 xa[4];
#pragma unroll
    for (int kc = 0; kc < 4; ++kc)
      xa[kc] = pack8(*(const f32x4*)(xp + kc * 32), *(const f32x4*)(xp + kc * 32 + 4));
#pragma unroll
    for (int g = 0; g < 4; ++g) {
      f32x4 a = {0.f, 0.f, 0.f, 0.f};
#pragma unroll
      for (int kc = 0; kc < 4; ++kc)
        a = __builtin_amdgcn_mfma_f32_16x16x32_bf16(xa[kc], bWx[g][kc], a, 0, 0, 0);
      // pure-C RNE pack of the acc, stored immediately (R10-verified)
      const unsigned p0 = ((unsigned)f2bf(a[1]) << 16) | (unsigned)f2bf(a[0]);
      const unsigned p1 = ((unsigned)f2bf(a[3]) << 16) | (unsigned)f2bf(a[2]);
      zp[g * 2]     = p0;
      zp[g * 2 + 1] = p1;
    }
    xp += 16 * F_;
    zp += 8 * 64 * 8;
  }
}

// ====== kernel 2: 64 blocks x 4 real rows, 4-way mirror; 1 row/lane activation ======
// All four lk groups hold identical D fragments (A rows m*4+rr == real row rr).
// Lane group lk activates real row lk only; publishes to fragment rows {lk,lk+4,lk+8,lk+12}.
__global__ __launch_bounds__(512, 1)
void lstm_zxb4_kernel(const unsigned* __restrict__ ZB, const float* __restrict__ ST,
                      const float* __restrict__ DN, const float* __restrict__ WH,
                      float* __restrict__ OUT)
{
  __shared__ __align__(16) short hbuf[2][16 * U_];

  const int tid  = threadIdx.x;
  const int w    = tid >> 6;
  const int lane = tid & 63;
  const int lr   = lane & 15;
  const int lk   = lane >> 4;
  const int rl   = lk;                 // owned real row 0..3
  const int b0   = blockIdx.x * 4;
  const int uu   = w * 16 + lr;

  const int doff1 = b0 + rl;                 // this lane's done
  const int ooff1 = (b0 + rl) * U_ + uu;     // this lane's OUT row

  // publish addresses (shorts), thread-constant: fragment rows rl+4m, m=0..3
  const int hP0 = (rl +  0) * U_ + ((((uu >> 3) ^ (rl +  0)) & 15) * 8) + (uu & 7);
  const int hP1 = (rl +  4) * U_ + ((((uu >> 3) ^ (rl +  4)) & 15) * 8) + (uu & 7);
  const int hP2 = (rl +  8) * U_ + ((((uu >> 3) ^ (rl +  8)) & 15) * 8) + (uu & 7);
  const int hP3 = (rl + 12) * U_ + ((((uu >> 3) ^ (rl + 12)) & 15) * 8) + (uu & 7);

  // Wh, pre-scaled per gate (log2e; 2*log2e for u)
  s16x8 bWh[4][4];
#pragma unroll
  for (int g = 0; g < 4; ++g) {
    const float scl = (g == 3) ? 2.0f * L2E : L2E;
    const int col = g * 128 + uu;
#pragma unroll
    for (int kc = 0; kc < 4; ++kc) {
      s16x8 wh;
#pragma unroll
      for (int e = 0; e < 8; ++e) {
        const int k = kc * 32 + lk * 8 + e;
        wh[e] = (short)f2bf(WH[k * G4_ + col] * scl);
      }
      bWh[g][kc] = wh;
    }
  }

  // fp32 state: 1 row per lane
  float c  = ST[doff1 * U_ + uu];
  float hn = ST[(B_ + doff1) * U_ + uu];
  { // mask m(0), publish to all 4 mirror slots
    const float m = 1.0f - DN[doff1];
    c *= m;
    const unsigned short hv = f2bf(hn * m);
    hbuf[0][hP0] = (short)hv;  hbuf[0][hP1] = (short)hv;
    hbuf[0][hP2] = (short)hv;  hbuf[0][hP3] = (short)hv;
  }

  // zx thread-const dword offset: writer tile bx>>2, writer lane group bx&3.
  // Each (tile, quarter) is read by exactly one block -> no duplicate traffic.
  const int zoff = ((((int)blockIdx.x >> 2) * 8 + w) * 64 + ((int)blockIdx.x & 3) * 16 + lr) * 8;

  u32x4 zA0, zA1, zB0, zB1;
  float dv;
  zA0 = *(const u32x4*)(ZB + zoff);
  zA1 = *(const u32x4*)(ZB + zoff + 4);
  zB0 = *(const u32x4*)(ZB + ZSTR8 + zoff);
  zB1 = *(const u32x4*)(ZB + ZSTR8 + zoff + 4);
  dv = DN[B_ + doff1];
  sync_lds();  // h(0) visible

  // step: tz/td/to are loop-uniform element offsets (SGPR-side stepping)
  auto step = [&](const int p, const bool pub, const bool pre,
                  u32x4& zq0, u32x4& zq1, const int tz, const int td, const int to) {
    // a) h(t) fragments from swizzled LDS
    s16x8 ah[4];
#pragma unroll
    for (int kc = 0; kc < 4; ++kc) {
      const int sl = (kc * 4 + lk) ^ lr;
      ah[kc] = *(const s16x8*)&hbuf[p][lr * U_ + sl * 8];
    }
    // b) decode bf16 zx -> f32 C-init, z = zx + h @ Wh
    f32x4 az[4];
#pragma unroll
    for (int g = 0; g < 4; ++g) {
      const unsigned d0 = (g < 2) ? zq0[(g & 1) * 2]     : zq1[(g & 1) * 2];
      const unsigned d1 = (g < 2) ? zq0[(g & 1) * 2 + 1] : zq1[(g & 1) * 2 + 1];
      f32x4 a = { bitsf(d0 << 16), bitsf(d0 & 0xFFFF0000u),
                  bitsf(d1 << 16), bitsf(d1 & 0xFFFF0000u) };
#pragma unroll
      for (int kc = 0; kc < 4; ++kc)
        a = __builtin_amdgcn_mfma_f32_16x16x32_bf16(ah[kc], bWh[g][kc], a, 0, 0, 0);
      az[g] = a;
    }
    // c) refill zx(t+2) — uniform base + const voffset
    if (pre) {
      zq0 = *(const u32x4*)(ZB + tz + zoff);
      zq1 = *(const u32x4*)(ZB + tz + zoff + 4);
    }
    // d) activation for this lane's SINGLE row (r = lk; R8-proven extract form)
    {
      const float z0 = az[0][rl];
      const float z1 = az[1][rl];
      const float z2 = az[2][rl];
      const float z3 = az[3][rl];
      const float eA = EXP2(-z0);
      const float eC = EXP2(-z1);
      const float eD = EXP2(-z2);
      const float eB = EXP2(-z3);
      const float iu = (1.0f - eB) * __builtin_amdgcn_rcpf((1.0f + eA) * (1.0f + eB));
      const float fg = __builtin_amdgcn_rcpf(1.0f + eC);
      const float cn = fmaf(fg, c, iu);
      const float ce = fminf(fmaxf(cn, -15.0f), 15.0f);
      const float eE = EXP2(ce * (-2.0f * L2E));
      const float h  = (1.0f - eE) * __builtin_amdgcn_rcpf((1.0f + eD) * (1.0f + eE));
      c  = cn;
      hn = h;
      OUT[to + ooff1] = h;
    }
    // e) done for t+1 (held), issue d(t+2)
    const float dcur = dv;
    if (pre) dv = DN[td + doff1];
    // f) mask m(t+1), publish to 4 mirror slots (no cross-lane exchange)
    if (pub) {
      const float m = 1.0f - dcur;
      c *= m;
      const unsigned short hv = f2bf(hn * m);
      short* hb = hbuf[p ^ 1];
      hb[hP0] = (short)hv;  hb[hP1] = (short)hv;
      hb[hP2] = (short)hv;  hb[hP3] = (short)hv;
    }
    sync_lds();
  };

  for (int t = 0; t < T_; t += 2) {
    step(0, true, t + 2 < T_, zA0, zA1,
         (t + 2) * ZSTR8, (t + 2) * B_, t * (B_ * U_));
    step(1, t + 2 < T_, t + 3 < T_, zB0, zB1,
         (t + 3) * ZSTR8, (t + 3) * B_, (t + 1) * (B_ * U_));
  }

  // final carry (c, h) after step T-1, unmasked — 1 row per lane
  const long fb = (long)T_ * B_ * U_;
  OUT[fb + (long)doff1 * U_ + uu]                 = c;
  OUT[fb + (long)B_ * U_ + (long)doff1 * U_ + uu] = hn;
}

// ============ fallback (R3 kernel verbatim): used when ws is too small ============
__global__ __launch_bounds__(512, 1)
void lstm_fb_kernel(const float* __restrict__ X, const float* __restrict__ ST,
                    const float* __restrict__ DN, const float* __restrict__ WX,
                    const float* __restrict__ WH, float* __restrict__ OUT)
{
  __shared__ __align__(16) short hbuf[2][16 * U_];

  const int tid  = threadIdx.x;
  const int w    = tid >> 6;
  const int lane = tid & 63;
  const int lr   = lane & 15;
  const int lk   = lane >> 4;
  const int b0   = blockIdx.x * 16;
  const int row0 = lk * 4;
  const int uu   = w * 16 + lr;

  const int xoff = (b0 + lr) * F_ + lk * 8;
  const int doff = b0 + row0;
  const int ooff = (b0 + row0) * U_ + uu;

  s16x8 bWh[4][4], bWx[4][4];
#pragma unroll
  for (int g = 0; g < 4; ++g) {
    const int col = g * 128 + uu;
#pragma unroll
    for (int kc = 0; kc < 4; ++kc) {
      s16x8 wh, wx;
#pragma unroll
      for (int e = 0; e < 8; ++e) {
        const int k = kc * 32 + lk * 8 + e;
        wh[e] = (short)f2bf(WH[k * G4_ + col]);
        wx[e] = (short)f2bf(WX[k * G4_ + col]);
      }
      bWh[g][kc] = wh;
      bWx[g][kc] = wx;
    }
  }

  float c[4], hn[4];
#pragma unroll
  for (int r = 0; r < 4; ++r) {
    c[r]  = ST[(b0 + row0 + r) * U_ + uu];
    hn[r] = ST[(B_ + b0 + row0 + r) * U_ + uu];
  }
  {
    f32x4 d = *(const f32x4*)&DN[doff];
#pragma unroll
    for (int r = 0; r < 4; ++r) {
      const float m = 1.0f - d[r];
      c[r] *= m;
      const int row = row0 + r;
      const int sl  = (uu >> 3) ^ row;
      hbuf[0][row * U_ + sl * 8 + (uu & 7)] = (short)cvt_pk_bf16(hn[r] * m, 0.f);
    }
  }

  f32x4 xv0[4], xv1[4], dv;
  f32x4 accA[4], accB[4];
  {
    const float* xp = X + xoff;
    s16x8 xa[4];
#pragma unroll
    for (int kc = 0; kc < 4; ++kc)
      xa[kc] = pack8(*(const f32x4*)(xp + kc * 32), *(const f32x4*)(xp + kc * 32 + 4));
#pragma unroll
    for (int g = 0; g < 4; ++g) {
      f32x4 a = {0.f, 0.f, 0.f, 0.f};
#pragma unroll
      for (int kc = 0; kc < 4; ++kc)
        a = __builtin_amdgcn_mfma_f32_16x16x32_bf16(xa[kc], bWx[g][kc], a, 0, 0, 0);
      accA[g] = a;
    }
#pragma unroll
    for (int kc = 0; kc < 4; ++kc) {
      xv0[kc] = *(const f32x4*)(X + B_ * F_ + xoff + kc * 32);
      xv1[kc] = *(const f32x4*)(X + B_ * F_ + xoff + kc * 32 + 4);
    }
    dv = *(const f32x4*)(DN + B_ + doff);
  }
  sync_lds();

  const float* Xt  = X + 2 * B_ * F_;
  const float* DNt = DN + 2 * B_;
  float*       Ot  = OUT;

  auto step = [&](const int p, const bool act_x, const bool pre_x,
                  f32x4 (&accZ)[4], f32x4 (&accX)[4]) {
    s16x8 ah[4];
#pragma unroll
    for (int kc = 0; kc < 4; ++kc) {
      const int sl = (kc * 4 + lk) ^ lr;
      ah[kc] = *(const s16x8*)&hbuf[p][lr * U_ + sl * 8];
    }
#pragma unroll
    for (int g = 0; g < 4; ++g) {
      f32x4 a = accZ[g];
#pragma unroll
      for (int kc = 0; kc < 4; ++kc)
        a = __builtin_amdgcn_mfma_f32_16x16x32_bf16(ah[kc], bWh[g][kc], a, 0, 0, 0);
      accZ[g] = a;
    }
#pragma unroll
    for (int r = 0; r < 4; ++r) {
      const float eA = __expf(-accZ[0][r]);
      const float eB = __expf(-2.0f * accZ[3][r]);
      const float eC = __expf(-accZ[1][r]);
      const float eD = __expf(-accZ[2][r]);
      const float iu = (1.0f - eB) * __builtin_amdgcn_rcpf((1.0f + eA) * (1.0f + eB));
      const float fg = __builtin_amdgcn_rcpf(1.0f + eC);
      const float cn = fmaf(fg, c[r], iu);
      const float ce = fminf(fmaxf(cn, -30.0f), 30.0f);
      const float eE = __expf(-2.0f * ce);
      const float h  = (1.0f - eE) * __builtin_amdgcn_rcpf((1.0f + eD) * (1.0f + eE));
      c[r]  = cn;
      hn[r] = h;
      Ot[ooff + r * U_] = h;
    }
    if (act_x) {
      s16x8 xa[4];
#pragma unroll
      for (int kc = 0; kc < 4; ++kc) xa[kc] = pack8(xv0[kc], xv1[kc]);
#pragma unroll
      for (int g = 0; g < 4; ++g) {
        f32x4 a = {0.f, 0.f, 0.f, 0.f};
#pragma unroll
        for (int kc = 0; kc < 4; ++kc)
          a = __builtin_amdgcn_mfma_f32_16x16x32_bf16(xa[kc], bWx[g][kc], a, 0, 0, 0);
        accX[g] = a;
      }
    }
    f32x4 dcur = dv;
    if (pre_x) {
#pragma unroll
      for (int kc = 0; kc < 4; ++kc) {
        xv0[kc] = *(const f32x4*)(Xt + xoff + kc * 32);
        xv1[kc] = *(const f32x4*)(Xt + xoff + kc * 32 + 4);
      }
      dv = *(const f32x4*)(DNt + doff);
    }
    if (act_x) {
#pragma unroll
      for (int r = 0; r < 4; ++r) {
        const float m = 1.0f - dcur[r];
        c[r] *= m;
        const int row = row0 + r;
        const int sl  = (uu >> 3) ^ row;
        hbuf[p ^ 1][row * U_ + sl * 8 + (uu & 7)] = (short)cvt_pk_bf16(hn[r] * m, 0.f);
      }
    }
    sync_lds();
  };

  for (int t = 0; t < T_; t += 2) {
    step(0, true, t + 2 < T_, accA, accB);
    Xt += B_ * F_; DNt += B_; Ot += B_ * U_;
    step(1, t + 2 < T_, t + 3 < T_, accB, accA);
    Xt += B_ * F_; DNt += B_; Ot += B_ * U_;
  }

  const long fb = (long)T_ * B_ * U_;
#pragma unroll
  for (int r = 0; r < 4; ++r) {
    OUT[fb + (long)(b0 + row0 + r) * U_ + uu]                 = c[r];
    OUT[fb + (long)B_ * U_ + (long)(b0 + row0 + r) * U_ + uu] = hn[r];
  }
}

extern "C" void kernel_launch(void* const* d_in, const int* in_sizes, int n_in,
                              void* d_out, int out_size, void* d_ws, size_t ws_size,
                              hipStream_t stream) {
  const float* X  = (const float*)d_in[0];  // [T,B,F]
  const float* ST = (const float*)d_in[1];  // [2,B,U]
  const float* DN = (const float*)d_in[2];  // [T,B]
  const float* WX = (const float*)d_in[3];  // [F,4U]
  const float* WH = (const float*)d_in[4];  // [U,4U]
  float* OUT = (float*)d_out;               // [T*B*U + 2*B*U]

  if (ws_size >= ZB_BYTES) {
    unsigned* ZB = (unsigned*)d_ws;
    zxb_gemm_kernel<<<dim3(256), dim3(512), 0, stream>>>(X, WX, ZB);
    lstm_zxb4_kernel<<<dim3(NBLK), dim3(512), 0, stream>>>(ZB, ST, DN, WH, OUT);
  } else {
    lstm_fb_kernel<<<dim3(16), dim3(512), 0, stream>>>(X, ST, DN, WX, WH, OUT);
  }
}

// Round 12
// 408.596 us; speedup vs baseline: 3.7646x; 1.0186x over previous
//
#include <hip/hip_runtime.h>

#define T_  512
#define B_  256
#define F_  128
#define U_  128
#define G4_ 512
#define L2E 1.4426950408889634f
#define NBLK 64                              // recurrent blocks (4 real rows each)
#define ZSTR8 (16 * 512 * 8)                 // zx-bf16 dwords per timestep
#define ZB_BYTES ((size_t)T_ * B_ * G4_ * 2) // 134217728

using f32x4 = __attribute__((ext_vector_type(4))) float;
using s16x8 = __attribute__((ext_vector_type(8))) short;
using u32x4 = __attribute__((ext_vector_type(4))) unsigned int;

#if __has_builtin(__builtin_amdgcn_exp2f)
#define EXP2(x) __builtin_amdgcn_exp2f(x)    // bare v_exp_f32, no libcall
#else
#define EXP2(x) exp2f(x)
#endif

__device__ __forceinline__ unsigned fbits(float f) { return __builtin_bit_cast(unsigned, f); }
__device__ __forceinline__ float bitsf(unsigned u) { return __builtin_bit_cast(float, u); }

// pure-C RNE fp32->bf16 (verified since R1; NO inline asm)
__device__ __forceinline__ unsigned short f2bf(float f) {
  unsigned u = fbits(f);
  u += 0x7FFFu + ((u >> 16) & 1u);
  return (unsigned short)(u >> 16);
}
// hardware RNE pack — VALU/loaded values only (never on MFMA acc: R9 lesson)
__device__ __forceinline__ unsigned cvt_pk_bf16(float lo, float hi) {
  unsigned r;
  asm("v_cvt_pk_bf16_f32 %0, %1, %2" : "=v"(r) : "v"(lo), "v"(hi));
  return r;
}
__device__ __forceinline__ s16x8 pack8(f32x4 a, f32x4 b) {
  u32x4 w;
  w[0] = cvt_pk_bf16(a[0], a[1]);
  w[1] = cvt_pk_bf16(a[2], a[3]);
  w[2] = cvt_pk_bf16(b[0], b[1]);
  w[3] = cvt_pk_bf16(b[2], b[3]);
  return __builtin_bit_cast(s16x8, w);
}
// barrier waiting only on LDS ops — global loads/stores stay in flight
__device__ __forceinline__ void sync_lds() {
  asm volatile("s_waitcnt lgkmcnt(0)\n\ts_barrier" ::: "memory");
}

// ====== kernel 1: R10 body verbatim; grid 512 x 16 iters, 2 blocks/CU for TLP ======
__global__ __launch_bounds__(512, 2)
void zxb_gemm_kernel(const float* __restrict__ X, const float* __restrict__ WX,
                     unsigned* __restrict__ ZB)
{
  const int tid  = threadIdx.x;
  const int w    = tid >> 6;
  const int lane = tid & 63;
  const int lr   = lane & 15;
  const int lk   = lane >> 4;

  s16x8 bWx[4][4];
#pragma unroll
  for (int g = 0; g < 4; ++g) {
    const float scl = (g == 3) ? 2.0f * L2E : L2E;   // u-gate carries tanh's 2x
    const int col = g * 128 + w * 16 + lr;
#pragma unroll
    for (int kc = 0; kc < 4; ++kc) {
      s16x8 wx;
#pragma unroll
      for (int e = 0; e < 8; ++e) {
        const int k = kc * 32 + lk * 8 + e;
        wx[e] = (short)f2bf(WX[k * G4_ + col] * scl);
      }
      bWx[g][kc] = wx;
    }
  }

  const int G0 = blockIdx.x * 16;
  const float* xp = X + (size_t)(G0 * 16 + lr) * F_ + lk * 8;
  unsigned*    zp = ZB + ((size_t)(G0 * 8 + w) * 64 + lane) * 8;

  for (int grp = 0; grp < 16; ++grp) {
    s16x8 xa[4];
#pragma unroll
    for (int kc = 0; kc < 4; ++kc)
      xa[kc] = pack8(*(const f32x4*)(xp + kc * 32), *(const f32x4*)(xp + kc * 32 + 4));
#pragma unroll
    for (int g = 0; g < 4; ++g) {
      f32x4 a = {0.f, 0.f, 0.f, 0.f};
#pragma unroll
      for (int kc = 0; kc < 4; ++kc)
        a = __builtin_amdgcn_mfma_f32_16x16x32_bf16(xa[kc], bWx[g][kc], a, 0, 0, 0);
      // pure-C RNE pack of the acc, stored immediately (R10-verified)
      const unsigned p0 = ((unsigned)f2bf(a[1]) << 16) | (unsigned)f2bf(a[0]);
      const unsigned p1 = ((unsigned)f2bf(a[3]) << 16) | (unsigned)f2bf(a[2]);
      zp[g * 2]     = p0;
      zp[g * 2 + 1] = p1;
    }
    xp += 16 * F_;
    zp += 8 * 64 * 8;
  }
}

// ====== kernel 2: R11 structure; h-tile shrunk to 4 REAL rows (broadcast reads) ======
// Fragment row fr holds real row fr&3 (R11 invariant). Store only [4][128] bf16,
// slot-swizzled s' = s ^ (r<<2); mirror lanes read the same address -> LDS broadcast.
__global__ __launch_bounds__(512, 1)
void lstm_zxb4_kernel(const unsigned* __restrict__ ZB, const float* __restrict__ ST,
                      const float* __restrict__ DN, const float* __restrict__ WH,
                      float* __restrict__ OUT)
{
  __shared__ __align__(16) short hbuf[2][4 * U_];   // 1 KB per buffer

  const int tid  = threadIdx.x;
  const int w    = tid >> 6;
  const int lane = tid & 63;
  const int lr   = lane & 15;
  const int lk   = lane >> 4;
  const int rl   = lk;                 // owned real row 0..3
  const int rr   = lr & 3;             // A-fragment source row (real)
  const int b0   = blockIdx.x * 4;
  const int uu   = w * 16 + lr;

  const int doff1 = b0 + rl;                 // this lane's done
  const int ooff1 = (b0 + rl) * U_ + uu;     // this lane's OUT row

  // publish address (shorts), thread-constant: row rl, slot (uu>>3)^(rl<<2), elem uu&7
  const int hP = rl * U_ + (((uu >> 3) ^ (rl << 2)) * 8) + (uu & 7);

  // Wh, pre-scaled per gate (log2e; 2*log2e for u)
  s16x8 bWh[4][4];
#pragma unroll
  for (int g = 0; g < 4; ++g) {
    const float scl = (g == 3) ? 2.0f * L2E : L2E;
    const int col = g * 128 + uu;
#pragma unroll
    for (int kc = 0; kc < 4; ++kc) {
      s16x8 wh;
#pragma unroll
      for (int e = 0; e < 8; ++e) {
        const int k = kc * 32 + lk * 8 + e;
        wh[e] = (short)f2bf(WH[k * G4_ + col] * scl);
      }
      bWh[g][kc] = wh;
    }
  }

  // fp32 state: 1 row per lane
  float c  = ST[doff1 * U_ + uu];
  float hn = ST[(B_ + doff1) * U_ + uu];
  { // mask m(0), publish (single write; mirrors now read-side broadcast)
    const float m = 1.0f - DN[doff1];
    c *= m;
    hbuf[0][hP] = (short)f2bf(hn * m);
  }

  // zx thread-const dword offset (R11-verified remap)
  const int zoff = ((((int)blockIdx.x >> 2) * 8 + w) * 64 + ((int)blockIdx.x & 3) * 16 + lr) * 8;

  u32x4 zA0, zA1, zB0, zB1;
  float dv;
  zA0 = *(const u32x4*)(ZB + zoff);
  zA1 = *(const u32x4*)(ZB + zoff + 4);
  zB0 = *(const u32x4*)(ZB + ZSTR8 + zoff);
  zB1 = *(const u32x4*)(ZB + ZSTR8 + zoff + 4);
  dv = DN[B_ + doff1];
  sync_lds();  // h(0) visible

  // step: tz/td/to are loop-uniform element offsets (SGPR-side stepping)
  auto step = [&](const int p, const bool pub, const bool pre,
                  u32x4& zq0, u32x4& zq1, const int tz, const int td, const int to) {
    // a) h(t) A-fragments: read real row rr, slot (kc*4+lk)^(rr<<2) — 4x broadcast
    s16x8 ah[4];
#pragma unroll
    for (int kc = 0; kc < 4; ++kc) {
      const int sl = (kc * 4 + lk) ^ (rr << 2);
      ah[kc] = *(const s16x8*)&hbuf[p][rr * U_ + sl * 8];
    }
    // b) decode bf16 zx -> f32 C-init, z = zx + h @ Wh
    f32x4 az[4];
#pragma unroll
    for (int g = 0; g < 4; ++g) {
      const unsigned d0 = (g < 2) ? zq0[(g & 1) * 2]     : zq1[(g & 1) * 2];
      const unsigned d1 = (g < 2) ? zq0[(g & 1) * 2 + 1] : zq1[(g & 1) * 2 + 1];
      f32x4 a = { bitsf(d0 << 16), bitsf(d0 & 0xFFFF0000u),
                  bitsf(d1 << 16), bitsf(d1 & 0xFFFF0000u) };
#pragma unroll
      for (int kc = 0; kc < 4; ++kc)
        a = __builtin_amdgcn_mfma_f32_16x16x32_bf16(ah[kc], bWh[g][kc], a, 0, 0, 0);
      az[g] = a;
    }
    // c) refill zx(t+2) — uniform base + const voffset
    if (pre) {
      zq0 = *(const u32x4*)(ZB + tz + zoff);
      zq1 = *(const u32x4*)(ZB + tz + zoff + 4);
    }
    // d) activation for this lane's SINGLE row (r = lk)
    {
      const float z0 = az[0][rl];
      const float z1 = az[1][rl];
      const float z2 = az[2][rl];
      const float z3 = az[3][rl];
      const float eA = EXP2(-z0);
      const float eC = EXP2(-z1);
      const float eD = EXP2(-z2);
      const float eB = EXP2(-z3);
      const float iu = (1.0f - eB) * __builtin_amdgcn_rcpf((1.0f + eA) * (1.0f + eB));
      const float fg = __builtin_amdgcn_rcpf(1.0f + eC);
      const float cn = fmaf(fg, c, iu);
      const float ce = fminf(fmaxf(cn, -15.0f), 15.0f);
      const float eE = EXP2(ce * (-2.0f * L2E));
      const float h  = (1.0f - eE) * __builtin_amdgcn_rcpf((1.0f + eD) * (1.0f + eE));
      c  = cn;
      hn = h;
      OUT[to + ooff1] = h;
    }
    // e) done for t+1 (held), issue d(t+2)
    const float dcur = dv;
    if (pre) dv = DN[td + doff1];
    // f) mask m(t+1), publish single short
    if (pub) {
      const float m = 1.0f - dcur;
      c *= m;
      hbuf[p ^ 1][hP] = (short)f2bf(hn * m);
    }
    sync_lds();
  };

  for (int t = 0; t < T_; t += 2) {
    step(0, true, t + 2 < T_, zA0, zA1,
         (t + 2) * ZSTR8, (t + 2) * B_, t * (B_ * U_));
    step(1, t + 2 < T_, t + 3 < T_, zB0, zB1,
         (t + 3) * ZSTR8, (t + 3) * B_, (t + 1) * (B_ * U_));
  }

  // final carry (c, h) after step T-1, unmasked — 1 row per lane
  const long fb = (long)T_ * B_ * U_;
  OUT[fb + (long)doff1 * U_ + uu]                 = c;
  OUT[fb + (long)B_ * U_ + (long)doff1 * U_ + uu] = hn;
}

// ============ fallback (R3 kernel verbatim): used when ws is too small ============
__global__ __launch_bounds__(512, 1)
void lstm_fb_kernel(const float* __restrict__ X, const float* __restrict__ ST,
                    const float* __restrict__ DN, const float* __restrict__ WX,
                    const float* __restrict__ WH, float* __restrict__ OUT)
{
  __shared__ __align__(16) short hbuf[2][16 * U_];

  const int tid  = threadIdx.x;
  const int w    = tid >> 6;
  const int lane = tid & 63;
  const int lr   = lane & 15;
  const int lk   = lane >> 4;
  const int b0   = blockIdx.x * 16;
  const int row0 = lk * 4;
  const int uu   = w * 16 + lr;

  const int xoff = (b0 + lr) * F_ + lk * 8;
  const int doff = b0 + row0;
  const int ooff = (b0 + row0) * U_ + uu;

  s16x8 bWh[4][4], bWx[4][4];
#pragma unroll
  for (int g = 0; g < 4; ++g) {
    const int col = g * 128 + uu;
#pragma unroll
    for (int kc = 0; kc < 4; ++kc) {
      s16x8 wh, wx;
#pragma unroll
      for (int e = 0; e < 8; ++e) {
        const int k = kc * 32 + lk * 8 + e;
        wh[e] = (short)f2bf(WH[k * G4_ + col]);
        wx[e] = (short)f2bf(WX[k * G4_ + col]);
      }
      bWh[g][kc] = wh;
      bWx[g][kc] = wx;
    }
  }

  float c[4], hn[4];
#pragma unroll
  for (int r = 0; r < 4; ++r) {
    c[r]  = ST[(b0 + row0 + r) * U_ + uu];
    hn[r] = ST[(B_ + b0 + row0 + r) * U_ + uu];
  }
  {
    f32x4 d = *(const f32x4*)&DN[doff];
#pragma unroll
    for (int r = 0; r < 4; ++r) {
      const float m = 1.0f - d[r];
      c[r] *= m;
      const int row = row0 + r;
      const int sl  = (uu >> 3) ^ row;
      hbuf[0][row * U_ + sl * 8 + (uu & 7)] = (short)cvt_pk_bf16(hn[r] * m, 0.f);
    }
  }

  f32x4 xv0[4], xv1[4], dv;
  f32x4 accA[4], accB[4];
  {
    const float* xp = X + xoff;
    s16x8 xa[4];
#pragma unroll
    for (int kc = 0; kc < 4; ++kc)
      xa[kc] = pack8(*(const f32x4*)(xp + kc * 32), *(const f32x4*)(xp + kc * 32 + 4));
#pragma unroll
    for (int g = 0; g < 4; ++g) {
      f32x4 a = {0.f, 0.f, 0.f, 0.f};
#pragma unroll
      for (int kc = 0; kc < 4; ++kc)
        a = __builtin_amdgcn_mfma_f32_16x16x32_bf16(xa[kc], bWx[g][kc], a, 0, 0, 0);
      accA[g] = a;
    }
#pragma unroll
    for (int kc = 0; kc < 4; ++kc) {
      xv0[kc] = *(const f32x4*)(X + B_ * F_ + xoff + kc * 32);
      xv1[kc] = *(const f32x4*)(X + B_ * F_ + xoff + kc * 32 + 4);
    }
    dv = *(const f32x4*)(DN + B_ + doff);
  }
  sync_lds();

  const float* Xt  = X + 2 * B_ * F_;
  const float* DNt = DN + 2 * B_;
  float*       Ot  = OUT;

  auto step = [&](const int p, const bool act_x, const bool pre_x,
                  f32x4 (&accZ)[4], f32x4 (&accX)[4]) {
    s16x8 ah[4];
#pragma unroll
    for (int kc = 0; kc < 4; ++kc) {
      const int sl = (kc * 4 + lk) ^ lr;
      ah[kc] = *(const s16x8*)&hbuf[p][lr * U_ + sl * 8];
    }
#pragma unroll
    for (int g = 0; g < 4; ++g) {
      f32x4 a = accZ[g];
#pragma unroll
      for (int kc = 0; kc < 4; ++kc)
        a = __builtin_amdgcn_mfma_f32_16x16x32_bf16(ah[kc], bWh[g][kc], a, 0, 0, 0);
      accZ[g] = a;
    }
#pragma unroll
    for (int r = 0; r < 4; ++r) {
      const float eA = __expf(-accZ[0][r]);
      const float eB = __expf(-2.0f * accZ[3][r]);
      const float eC = __expf(-accZ[1][r]);
      const float eD = __expf(-accZ[2][r]);
      const float iu = (1.0f - eB) * __builtin_amdgcn_rcpf((1.0f + eA) * (1.0f + eB));
      const float fg = __builtin_amdgcn_rcpf(1.0f + eC);
      const float cn = fmaf(fg, c[r], iu);
      const float ce = fminf(fmaxf(cn, -30.0f), 30.0f);
      const float eE = __expf(-2.0f * ce);
      const float h  = (1.0f - eE) * __builtin_amdgcn_rcpf((1.0f + eD) * (1.0f + eE));
      c[r]  = cn;
      hn[r] = h;
      Ot[ooff + r * U_] = h;
    }
    if (act_x) {
      s16x8 xa[4];
#pragma unroll
      for (int kc = 0; kc < 4; ++kc) xa[kc] = pack8(xv0[kc], xv1[kc]);
#pragma unroll
      for (int g = 0; g < 4; ++g) {
        f32x4 a = {0.f, 0.f, 0.f, 0.f};
#pragma unroll
        for (int kc = 0; kc < 4; ++kc)
          a = __builtin_amdgcn_mfma_f32_16x16x32_bf16(xa[kc], bWx[g][kc], a, 0, 0, 0);
        accX[g] = a;
      }
    }
    f32x4 dcur = dv;
    if (pre_x) {
#pragma unroll
      for (int kc = 0; kc < 4; ++kc) {
        xv0[kc] = *(const f32x4*)(Xt + xoff + kc * 32);
        xv1[kc] = *(const f32x4*)(Xt + xoff + kc * 32 + 4);
      }
      dv = *(const f32x4*)(DNt + doff);
    }
    if (act_x) {
#pragma unroll
      for (int r = 0; r < 4; ++r) {
        const float m = 1.0f - dcur[r];
        c[r] *= m;
        const int row = row0 + r;
        const int sl  = (uu >> 3) ^ row;
        hbuf[p ^ 1][row * U_ + sl * 8 + (uu & 7)] = (short)cvt_pk_bf16(hn[r] * m, 0.f);
      }
    }
    sync_lds();
  };

  for (int t = 0; t < T_; t += 2) {
    step(0, true, t + 2 < T_, accA, accB);
    Xt += B_ * F_; DNt += B_; Ot += B_ * U_;
    step(1, t + 2 < T_, t + 3 < T_, accB, accA);
    Xt += B_ * F_; DNt += B_; Ot += B_ * U_;
  }

  const long fb = (long)T_ * B_ * U_;
#pragma unroll
  for (int r = 0; r < 4; ++r) {
    OUT[fb + (long)(b0 + row0 + r) * U_ + uu]                 = c[r];
    OUT[fb + (long)B_ * U_ + (long)(b0 + row0 + r) * U_ + uu] = hn[r];
  }
}

extern "C" void kernel_launch(void* const* d_in, const int* in_sizes, int n_in,
                              void* d_out, int out_size, void* d_ws, size_t ws_size,
                              hipStream_t stream) {
  const float* X  = (const float*)d_in[0];  // [T,B,F]
  const float* ST = (const float*)d_in[1];  // [2,B,U]
  const float* DN = (const float*)d_in[2];  // [T,B]
  const float* WX = (const float*)d_in[3];  // [F,4U]
  const float* WH = (const float*)d_in[4];  // [U,4U]
  float* OUT = (float*)d_out;               // [T*B*U + 2*B*U]

  if (ws_size >= ZB_BYTES) {
    unsigned* ZB = (unsigned*)d_ws;
    zxb_gemm_kernel<<<dim3(512), dim3(512), 0, stream>>>(X, WX, ZB);
    lstm_zxb4_kernel<<<dim3(NBLK), dim3(512), 0, stream>>>(ZB, ST, DN, WH, OUT);
  } else {
    lstm_fb_kernel<<<dim3(16), dim3(512), 0, stream>>>(X, ST, DN, WX, WH, OUT);
  }
}